// Round 10
// baseline (557.898 us; speedup 1.0000x reference)
//
#include <hip/hip_runtime.h>
#include <math.h>

#define N_NODES 20000
#define E_EDGES 320000
#define DIN     256
#define HHD     512
#define HIDD    64
#define NHEADS  8
#define K1N     15000
#define K2N     11250

typedef unsigned short u16;
typedef __attribute__((ext_vector_type(8))) short bf16x8;
typedef __attribute__((ext_vector_type(4))) float f32x4;

static inline int cdiv(long long a, long long b) { return (int)((a + b - 1) / b); }

__device__ __forceinline__ void atomicMaxF(float* addr, float val) {
  int* ai = (int*)addr;
  int old = __float_as_int(*addr);
  while (__int_as_float(old) < val) {
    int assumed = old;
    old = atomicCAS(ai, assumed, __float_as_int(val));
    if (old == assumed) break;
  }
}

__device__ __forceinline__ u16 f2bf(float x) {   // RNE f32 -> bf16 bits
  unsigned u = __float_as_uint(x);
  return (u16)((u + 0x7FFFu + ((u >> 16) & 1u)) >> 16);
}
__device__ __forceinline__ float bfval(u16 b) { return __uint_as_float(((unsigned)b) << 16); }

__device__ __forceinline__ void unpk8(uint4 u, float* v) {
  v[0] = __uint_as_float(u.x << 16); v[1] = __uint_as_float(u.x & 0xffff0000u);
  v[2] = __uint_as_float(u.y << 16); v[3] = __uint_as_float(u.y & 0xffff0000u);
  v[4] = __uint_as_float(u.z << 16); v[5] = __uint_as_float(u.z & 0xffff0000u);
  v[6] = __uint_as_float(u.w << 16); v[7] = __uint_as_float(u.w & 0xffff0000u);
}

// deg1=0, rank1=0, pools[1152]: [-inf x512, 0 x512, -inf x64, 0 x64]
__global__ void init_all(int* deg1, int* rank1, float* pools) {
  int i = blockIdx.x * blockDim.x + threadIdx.x;
  if (i < N_NODES) deg1[i] = 0;
  else if (i < 2 * N_NODES) rank1[i - N_NODES] = 0;
  else {
    int idx = i - 2 * N_NODES;
    if (idx < 1152)
      pools[idx] = (idx < 512 || (idx >= 1024 && idx < 1088)) ? -INFINITY : 0.f;
  }
}

// ---------------- fused bf16 hi/lo split conversion (A-part + W-part in one launch) ----------------
__global__ void conv_fused(const float* __restrict__ A, const int* __restrict__ perm,
                           const float* __restrict__ scalev,
                           u16* __restrict__ ah, u16* __restrict__ al, int M, int K,
                           const float* __restrict__ w1, const float* __restrict__ w2,
                           u16* __restrict__ wh, u16* __restrict__ wl, int ncHalf,
                           int aBlocks) {
  if ((int)blockIdx.x < aBlocks) {
    long long i = (long long)blockIdx.x * blockDim.x + threadIdx.x;
    long long e0 = i * 4;
    if (e0 >= (long long)M * K) return;
    int row = (int)(e0 / K), col = (int)(e0 % K);
    int ar = perm ? perm[row] : row;
    float4 v = *(const float4*)(A + (size_t)ar * K + col);
    if (scalev) { float s = scalev[ar]; v.x *= s; v.y *= s; v.z *= s; v.w *= s; }
    u16 h0 = f2bf(v.x), h1 = f2bf(v.y), h2 = f2bf(v.z), h3 = f2bf(v.w);
    u16 l0 = f2bf(v.x - bfval(h0)), l1 = f2bf(v.y - bfval(h1));
    u16 l2 = f2bf(v.z - bfval(h2)), l3 = f2bf(v.w - bfval(h3));
    uint2 hp, lp;
    hp.x = (unsigned)h0 | ((unsigned)h1 << 16); hp.y = (unsigned)h2 | ((unsigned)h3 << 16);
    lp.x = (unsigned)l0 | ((unsigned)l1 << 16); lp.y = (unsigned)l2 | ((unsigned)l3 << 16);
    *(uint2*)(ah + e0) = hp;
    *(uint2*)(al + e0) = lp;
  } else {
    int i = (blockIdx.x - aBlocks) * blockDim.x + threadIdx.x;
    int NT = 2 * ncHalf;
    if (i >= NT * K) return;
    int n = i % NT, k = i / NT;
    float v = (n < ncHalf) ? w1[(size_t)k * ncHalf + n] : w2[(size_t)k * ncHalf + (n - ncHalf)];
    u16 h = f2bf(v);
    u16 l = f2bf(v - bfval(h));
    wh[(size_t)n * K + k] = h;
    wl[(size_t)n * K + k] = l;
  }
}

// ---------------- split-bf16 MFMA GEMM: C = A @ [W1|W2]; OUTBF: store C as bf16 ----------------
template<int BT, bool OUTBF>
__global__ __launch_bounds__(256) void gemm_bf16x3(const u16* __restrict__ ah,
                                                   const u16* __restrict__ al,
                                                   const u16* __restrict__ wh,
                                                   const u16* __restrict__ wl,
                                                   void* __restrict__ c1v,
                                                   void* __restrict__ c2v,
                                                   int M, int K, int ncHalf) {
  constexpr int F = BT / 32;
  __shared__ u16 Ah[BT][40], Al[BT][40], Bh[BT][40], Bl[BT][40];
  int tid = threadIdx.x;
  int lane = tid & 63, wid = tid >> 6;
  int wr = (wid >> 1) * (BT / 2), wc = (wid & 1) * (BT / 2);
  int brow = blockIdx.y * BT, bcol = blockIdx.x * BT;
  int fr = lane & 15, kg = lane >> 4;
  f32x4 acc[F][F];
#pragma unroll
  for (int i = 0; i < F; i++)
#pragma unroll
    for (int j = 0; j < F; j++) acc[i][j] = (f32x4){0.f, 0.f, 0.f, 0.f};

  for (int k0 = 0; k0 < K; k0 += 32) {
    constexpr int ITER = (BT * 32) / (256 * 8);
#pragma unroll
    for (int i = 0; i < ITER; i++) {
      int pos = tid + i * 256;
      int row = pos >> 2;
      int kc = (pos & 3) * 8;
      int gr = brow + row;
      float4 z = make_float4(0.f, 0.f, 0.f, 0.f);
      float4 vah = (gr < M) ? *(const float4*)(ah + (size_t)gr * K + k0 + kc) : z;
      float4 val = (gr < M) ? *(const float4*)(al + (size_t)gr * K + k0 + kc) : z;
      *(float4*)(&Ah[row][kc]) = vah;
      *(float4*)(&Al[row][kc]) = val;
      int gn = bcol + row;
      *(float4*)(&Bh[row][kc]) = *(const float4*)(wh + (size_t)gn * K + k0 + kc);
      *(float4*)(&Bl[row][kc]) = *(const float4*)(wl + (size_t)gn * K + k0 + kc);
    }
    __syncthreads();
    bf16x8 fa_h[F], fa_l[F], fb_h[F], fb_l[F];
#pragma unroll
    for (int t = 0; t < F; t++) {
      fa_h[t] = *(const bf16x8*)(&Ah[wr + t * 16 + fr][kg * 8]);
      fa_l[t] = *(const bf16x8*)(&Al[wr + t * 16 + fr][kg * 8]);
      fb_h[t] = *(const bf16x8*)(&Bh[wc + t * 16 + fr][kg * 8]);
      fb_l[t] = *(const bf16x8*)(&Bl[wc + t * 16 + fr][kg * 8]);
    }
#pragma unroll
    for (int i = 0; i < F; i++)
#pragma unroll
      for (int j = 0; j < F; j++) {
        acc[i][j] = __builtin_amdgcn_mfma_f32_16x16x32_bf16(fa_h[i], fb_h[j], acc[i][j], 0, 0, 0);
        acc[i][j] = __builtin_amdgcn_mfma_f32_16x16x32_bf16(fa_h[i], fb_l[j], acc[i][j], 0, 0, 0);
        acc[i][j] = __builtin_amdgcn_mfma_f32_16x16x32_bf16(fa_l[i], fb_h[j], acc[i][j], 0, 0, 0);
      }
    __syncthreads();
  }
#pragma unroll
  for (int i = 0; i < F; i++) {
    int r0 = brow + wr + i * 16 + kg * 4;
#pragma unroll
    for (int j = 0; j < F; j++) {
      int cg = bcol + wc + j * 16 + fr;
      bool first = (cg < ncHalf);
      int cc = first ? cg : cg - ncHalf;
#pragma unroll
      for (int r = 0; r < 4; r++) {
        int gr = r0 + r;
        if (gr < M) {
          if (OUTBF) {
            u16* cp = first ? (u16*)c1v : (u16*)c2v;
            cp[(size_t)gr * ncHalf + cc] = f2bf(acc[i][j][r]);
          } else {
            float* cp = first ? (float*)c1v : (float*)c2v;
            cp[(size_t)gr * ncHalf + cc] = acc[i][j][r];
          }
        }
      }
    }
  }
}

// ---------------- CSR construction (stores mapped source id directly) ----------------
__global__ void deg_count(const int* __restrict__ src, const int* __restrict__ dst,
                          const int* __restrict__ newid, int* __restrict__ deg,
                          int nloops) {
  int i = blockIdx.x * blockDim.x + threadIdx.x;
  if (i >= E_EDGES + nloops) return;
  int d;
  if (i < E_EDGES) {
    if (newid) {
      int s = newid[src[i]]; d = newid[dst[i]];
      if (s < 0 || d < 0) return;
    } else d = dst[i];
  } else d = i - E_EDGES;
  atomicAdd(&deg[d], 1);
}

// shuffle-based single-block exclusive scan; cursor may alias deg.
__global__ __launch_bounds__(1024) void scan_excl(const int* deg, int* rowptr,
                                                  int* cursor, int n) {
  __shared__ int wsum[16];
  __shared__ int carry;
  int tid = threadIdx.x, lane = tid & 63, wid = tid >> 6;
  if (tid == 0) { carry = 0; rowptr[0] = 0; }
  __syncthreads();
  for (int base = 0; base < n; base += 1024) {
    int v = (base + tid < n) ? deg[base + tid] : 0;
    int s = v;
#pragma unroll
    for (int off = 1; off < 64; off <<= 1) {
      int t = __shfl_up(s, off);
      if (lane >= off) s += t;
    }
    if (lane == 63) wsum[wid] = s;
    __syncthreads();
    if (wid == 0) {
      int w = (lane < 16) ? wsum[lane] : 0;
#pragma unroll
      for (int off = 1; off < 16; off <<= 1) {
        int t = __shfl_up(w, off);
        if (lane >= off) w += t;
      }
      if (lane < 16) wsum[lane] = w;
    }
    __syncthreads();
    int incl = s + (wid > 0 ? wsum[wid - 1] : 0) + carry;
    if (base + tid < n) { rowptr[base + tid + 1] = incl; cursor[base + tid] = incl - v; }
    __syncthreads();
    if (tid == 1023) carry = incl;
    __syncthreads();
  }
}

__global__ void csr_scatter(const int* __restrict__ src, const int* __restrict__ dst,
                            const int* __restrict__ newid, int* __restrict__ cursor,
                            int* __restrict__ csr_s, int nloops) {
  int i = blockIdx.x * blockDim.x + threadIdx.x;
  if (i >= E_EDGES + nloops) return;
  int s, d;
  if (i < E_EDGES) {
    s = src[i]; d = dst[i];
    if (newid) {
      s = newid[s]; d = newid[d];
      if (s < 0 || d < 0) return;
    }
  } else s = d = i - E_EDGES;
  int pos = atomicAdd(&cursor[d], 1);
  csr_s[pos] = s;
}

// ---------------- Stage 1 fused GAT: 1 wave/node, bf16 gather, 4-deep prefetch ----------------
__global__ __launch_bounds__(256) void gat1_fused(const int* __restrict__ rowptr,
                                                  const int* __restrict__ csr_s,
                                                  const u16* __restrict__ xlb,
                                                  const u16* __restrict__ xrb,
                                                  const float* __restrict__ att,
                                                  const float* __restrict__ bias,
                                                  const float* __restrict__ pw,
                                                  float* __restrict__ out,
                                                  float* __restrict__ xls) {
  int lane = threadIdx.x & 63;
  long long t = (long long)blockIdx.x * blockDim.x + threadIdx.x;
  int d = (int)(t >> 6);
  if (d >= N_NODES) return;
  int base = lane * 8;                       // 8 cols/lane, head = lane>>3
  float4 a0 = *(const float4*)(att + base);
  float4 a1 = *(const float4*)(att + base + 4);
  float r[8];
  unpk8(*(const uint4*)(xrb + (size_t)d * HHD + base), r);
  float m = -INFINITY, den = 0.f;
  float acc[8] = {0.f, 0.f, 0.f, 0.f, 0.f, 0.f, 0.f, 0.f};
  int b0 = rowptr[d];
  int cnt = rowptr[d + 1] - b0;
  const int* sp = csr_s + b0;

  auto online = [&](uint4 u) {
    float v[8];
    unpk8(u, v);
    float p, tv;
    tv = v[0] + r[0]; tv = tv > 0.f ? tv : 0.2f * tv; p  = tv * a0.x;
    tv = v[1] + r[1]; tv = tv > 0.f ? tv : 0.2f * tv; p += tv * a0.y;
    tv = v[2] + r[2]; tv = tv > 0.f ? tv : 0.2f * tv; p += tv * a0.z;
    tv = v[3] + r[3]; tv = tv > 0.f ? tv : 0.2f * tv; p += tv * a0.w;
    tv = v[4] + r[4]; tv = tv > 0.f ? tv : 0.2f * tv; p += tv * a1.x;
    tv = v[5] + r[5]; tv = tv > 0.f ? tv : 0.2f * tv; p += tv * a1.y;
    tv = v[6] + r[6]; tv = tv > 0.f ? tv : 0.2f * tv; p += tv * a1.z;
    tv = v[7] + r[7]; tv = tv > 0.f ? tv : 0.2f * tv; p += tv * a1.w;
    p += __shfl_xor(p, 1); p += __shfl_xor(p, 2); p += __shfl_xor(p, 4);
    float nm = fmaxf(m, p);
    float w  = __expf(p - nm);
    float sc = __expf(m - nm);
    den = den * sc + w;
#pragma unroll
    for (int k = 0; k < 8; k++) acc[k] = acc[k] * sc + w * v[k];
    m = nm;
  };

  uint4 zz = make_uint4(0u, 0u, 0u, 0u);
  uint4 A = *(const uint4*)(xlb + (size_t)sp[0] * HHD + base);
  uint4 B = (cnt > 1) ? *(const uint4*)(xlb + (size_t)sp[1] * HHD + base) : zz;
  uint4 C = (cnt > 2) ? *(const uint4*)(xlb + (size_t)sp[2] * HHD + base) : zz;
  uint4 D = (cnt > 3) ? *(const uint4*)(xlb + (size_t)sp[3] * HHD + base) : zz;
  int j = 0;
  for (; j + 4 <= cnt; j += 4) {
    uint4 u = A;
    if (j + 4 < cnt) A = *(const uint4*)(xlb + (size_t)sp[j + 4] * HHD + base);
    online(u);
    u = B;
    if (j + 5 < cnt) B = *(const uint4*)(xlb + (size_t)sp[j + 5] * HHD + base);
    online(u);
    u = C;
    if (j + 6 < cnt) C = *(const uint4*)(xlb + (size_t)sp[j + 6] * HHD + base);
    online(u);
    u = D;
    if (j + 7 < cnt) D = *(const uint4*)(xlb + (size_t)sp[j + 7] * HHD + base);
    online(u);
  }
  if (j < cnt) {
    online(A);
    if (j + 1 < cnt) {
      online(B);
      if (j + 2 < cnt) online(C);
    }
  }

  float inv = 1.f / den;
  float4 b0v = *(const float4*)(bias + base);
  float4 b1v = *(const float4*)(bias + base + 4);
  float o[8];
  o[0] = acc[0] * inv + b0v.x; o[1] = acc[1] * inv + b0v.y;
  o[2] = acc[2] * inv + b0v.z; o[3] = acc[3] * inv + b0v.w;
  o[4] = acc[4] * inv + b1v.x; o[5] = acc[5] * inv + b1v.y;
  o[6] = acc[6] * inv + b1v.z; o[7] = acc[7] * inv + b1v.w;
#pragma unroll
  for (int k = 0; k < 8; k++) o[k] = o[k] > 0.f ? o[k] : 0.f;
  float* op = out + (size_t)d * HHD + base;
  *(float4*)(op)     = make_float4(o[0], o[1], o[2], o[3]);
  *(float4*)(op + 4) = make_float4(o[4], o[5], o[6], o[7]);
  float4 w0 = *(const float4*)(pw + base);
  float4 w1 = *(const float4*)(pw + base + 4);
  float sdot = o[0]*w0.x + o[1]*w0.y + o[2]*w0.z + o[3]*w0.w
             + o[4]*w1.x + o[5]*w1.y + o[6]*w1.z + o[7]*w1.w;
#pragma unroll
  for (int off = 32; off > 0; off >>= 1) sdot += __shfl_xor(sdot, off);
  if (lane == 0) xls[d] = sdot;
}

// ---------------- Stage 2 fused GAT: 4 nodes per wave (one per 16-lane group) ----------------
__global__ __launch_bounds__(256) void gat2_fused(const int* __restrict__ rowptr,
                                                  const int* __restrict__ csr_s,
                                                  const float* __restrict__ xl,
                                                  const float* __restrict__ xr,
                                                  const float* __restrict__ att,
                                                  const float* __restrict__ bias,
                                                  const float* __restrict__ pw,
                                                  float* __restrict__ out,
                                                  float* __restrict__ xls, int n) {
  int lane = threadIdx.x & 63;
  int grp = lane >> 4, li = lane & 15;
  long long t = (long long)blockIdx.x * blockDim.x + threadIdx.x;
  int wv = (int)(t >> 6);
  int d = wv * 4 + grp;
  if (d >= n) return;
  int c0 = li * 4;
  float4 av = *(const float4*)(att + c0);
  float4 rv = *(const float4*)(xr + (size_t)d * HIDD + c0);
  float m = -INFINITY, den = 0.f;
  float4 acc = make_float4(0.f, 0.f, 0.f, 0.f);
  int b0 = rowptr[d];
  int cnt = rowptr[d + 1] - b0;
  const int* sp = csr_s + b0;

  auto online = [&](float4 v) {
    float p, tv;
    tv = v.x + rv.x; tv = tv > 0.f ? tv : 0.2f * tv; p  = tv * av.x;
    tv = v.y + rv.y; tv = tv > 0.f ? tv : 0.2f * tv; p += tv * av.y;
    tv = v.z + rv.z; tv = tv > 0.f ? tv : 0.2f * tv; p += tv * av.z;
    tv = v.w + rv.w; tv = tv > 0.f ? tv : 0.2f * tv; p += tv * av.w;
    p += __shfl_xor(p, 1); p += __shfl_xor(p, 2); p += __shfl_xor(p, 4); p += __shfl_xor(p, 8);
    float nm = fmaxf(m, p);
    float w  = __expf(p - nm);
    float sc = __expf(m - nm);
    den = den * sc + w;
    acc.x = acc.x * sc + w * v.x;
    acc.y = acc.y * sc + w * v.y;
    acc.z = acc.z * sc + w * v.z;
    acc.w = acc.w * sc + w * v.w;
    m = nm;
  };

  float4 zz = make_float4(0.f, 0.f, 0.f, 0.f);
  float4 A = *(const float4*)(xl + (size_t)sp[0] * HIDD + c0);
  float4 B = (cnt > 1) ? *(const float4*)(xl + (size_t)sp[1] * HIDD + c0) : zz;
  int j = 0;
  for (; j + 2 <= cnt; j += 2) {
    float4 v = A;
    if (j + 2 < cnt) A = *(const float4*)(xl + (size_t)sp[j + 2] * HIDD + c0);
    online(v);
    v = B;
    if (j + 3 < cnt) B = *(const float4*)(xl + (size_t)sp[j + 3] * HIDD + c0);
    online(v);
  }
  if (j < cnt) online(A);

  float inv = 1.f / den;
  float4 bv = *(const float4*)(bias + c0);
  float4 o;
  o.x = acc.x * inv + bv.x; o.y = acc.y * inv + bv.y;
  o.z = acc.z * inv + bv.z; o.w = acc.w * inv + bv.w;
  o.x = o.x > 0.f ? o.x : 0.f; o.y = o.y > 0.f ? o.y : 0.f;
  o.z = o.z > 0.f ? o.z : 0.f; o.w = o.w > 0.f ? o.w : 0.f;
  *(float4*)(out + (size_t)d * HIDD + c0) = o;
  float4 wv4 = *(const float4*)(pw + c0);
  float sdot = o.x * wv4.x + o.y * wv4.y + o.z * wv4.z + o.w * wv4.w;
  sdot += __shfl_xor(sdot, 1); sdot += __shfl_xor(sdot, 2);
  sdot += __shfl_xor(sdot, 4); sdot += __shfl_xor(sdot, 8);
  if (li == 0) xls[d] = sdot;
}

// ---------------- pool scoring: online softmax + tanh, 4-deep prefetch ----------------
__global__ __launch_bounds__(256) void pool_score(const int* __restrict__ rowptr,
                                                  const int* __restrict__ csr_s,
                                                  const float* __restrict__ xls,
                                                  const float* __restrict__ asrc,
                                                  const float* __restrict__ adst,
                                                  const float* __restrict__ bias,
                                                  const float* __restrict__ sel,
                                                  float* __restrict__ score, int n) {
  int d = blockIdx.x * blockDim.x + threadIdx.x;
  if (d >= n) return;
  float as = asrc[0], ad = adst[0];
  float ar = xls[d] * ad;
  int b0 = rowptr[d];
  int cnt = rowptr[d + 1] - b0;
  const int* sp = csr_s + b0;
  float m = -INFINITY, den = 0.f, num = 0.f;
  auto upd = [&](float xs) {
    float e = xs * as + ar;
    e = e > 0.f ? e : 0.2f * e;
    float nm = fmaxf(m, e);
    float scv = __expf(m - nm);
    float ex = __expf(e - nm);
    den = den * scv + ex;
    num = num * scv + ex * xs;
    m = nm;
  };
  float xA = xls[sp[0]];
  float xB = (cnt > 1) ? xls[sp[1]] : 0.f;
  float xC = (cnt > 2) ? xls[sp[2]] : 0.f;
  float xD = (cnt > 3) ? xls[sp[3]] : 0.f;
  int j = 0;
  for (; j + 4 <= cnt; j += 4) {
    float x1 = xA;
    if (j + 4 < cnt) xA = xls[sp[j + 4]];
    upd(x1);
    float x2 = xB;
    if (j + 5 < cnt) xB = xls[sp[j + 5]];
    upd(x2);
    float x3 = xC;
    if (j + 6 < cnt) xC = xls[sp[j + 6]];
    upd(x3);
    float x4 = xD;
    if (j + 7 < cnt) xD = xls[sp[j + 7]];
    upd(x4);
  }
  if (j < cnt) {
    upd(xA);
    if (j + 1 < cnt) {
      upd(xB);
      if (j + 2 < cnt) upd(xC);
    }
  }
  float attn = num / den + bias[0];
  float sv = sel[0];
  score[d] = tanhf(attn * sv / fabsf(sv));
}

// ---------------- top-k rank counting, 4 nodes/thread (+optional zero-fill) ----------------
#define TK_CHUNK 512
__global__ __launch_bounds__(256) void topk_count(const float* __restrict__ score,
                                                  int* __restrict__ rank, int n,
                                                  int* __restrict__ zbuf, int zn) {
  __shared__ float sc[TK_CHUNK];
  if (zbuf) {
    long long fid = ((long long)blockIdx.y * gridDim.x + blockIdx.x) * 256 + threadIdx.x;
    if (fid < zn) zbuf[fid] = 0;
  }
  int i0 = (blockIdx.x * 256 + threadIdx.x) * 4;
  int base = blockIdx.y * TK_CHUNK;
  int cnt = min(TK_CHUNK, n - base);
  for (int j = threadIdx.x; j < cnt; j += 256) sc[j] = score[base + j];
  __syncthreads();
  if (i0 >= n) return;
  int nv = min(4, n - i0);
  float s0 = score[i0];
  float s1 = (nv > 1) ? score[i0 + 1] : 0.f;
  float s2 = (nv > 2) ? score[i0 + 2] : 0.f;
  float s3 = (nv > 3) ? score[i0 + 3] : 0.f;
  int r0 = 0, r1 = 0, r2 = 0, r3 = 0;
  for (int j = 0; j < cnt; j++) {
    float sj = sc[j];
    int gj = base + j;
    r0 += (sj > s0) || ((sj == s0) && (gj < i0));
    r1 += (sj > s1) || ((sj == s1) && (gj < i0 + 1));
    r2 += (sj > s2) || ((sj == s2) && (gj < i0 + 2));
    r3 += (sj > s3) || ((sj == s3) && (gj < i0 + 3));
  }
  if (r0) atomicAdd(&rank[i0], r0);
  if (nv > 1 && r1) atomicAdd(&rank[i0 + 1], r1);
  if (nv > 2 && r2) atomicAdd(&rank[i0 + 2], r2);
  if (nv > 3 && r3) atomicAdd(&rank[i0 + 3], r3);
}

__global__ void topk_assign(const int* __restrict__ rank, int* __restrict__ newid,
                            int* __restrict__ perm, int n, int k) {
  int i = blockIdx.x * blockDim.x + threadIdx.x;
  if (i < n) {
    int r = rank[i];
    newid[i] = (r < k) ? r : -1;
    if (r < k) perm[r] = i;
  }
}

// stage-1 column pool fused with stage-2 A-conversion (+W2 conversion in extra blocks)
__global__ __launch_bounds__(256) void col_pool_conv(const float* __restrict__ X,
                                                     const int* __restrict__ perm,
                                                     const float* __restrict__ scalev,
                                                     float* __restrict__ omax,
                                                     float* __restrict__ osum,
                                                     u16* __restrict__ ah, u16* __restrict__ al,
                                                     const float* __restrict__ w1,
                                                     const float* __restrict__ w2,
                                                     u16* __restrict__ wh, u16* __restrict__ wl,
                                                     int cpBlocks) {
  int tid = threadIdx.x;
  if ((int)blockIdx.x < cpBlocks) {
    float mx[2] = {-INFINITY, -INFINITY};
    float sm[2] = {0.f, 0.f};
    int rpb = (K1N + cpBlocks - 1) / cpBlocks;
    int rbeg = blockIdx.x * rpb;
    int rend = min(K1N, rbeg + rpb);
    for (int r = rbeg; r < rend; r++) {
      int orow = perm[r];
      float sc = scalev[orow];
      const float* row = X + (size_t)orow * HHD;
#pragma unroll
      for (int sg = 0; sg < 2; sg++) {
        int c = sg * 256 + tid;
        float v = row[c] * sc;
        mx[sg] = fmaxf(mx[sg], v);
        sm[sg] += v;
        u16 h = f2bf(v);
        u16 l = f2bf(v - bfval(h));
        ah[(size_t)r * HHD + c] = h;
        al[(size_t)r * HHD + c] = l;
      }
    }
    if (rbeg < rend) {
#pragma unroll
      for (int sg = 0; sg < 2; sg++) {
        int c = sg * 256 + tid;
        atomicMaxF(&omax[c], mx[sg]);
        atomicAdd(&osum[c], sm[sg]);
      }
    }
  } else {
    // W2 conversion: [HHD, HIDD] x2 -> wh/wl [2*HIDD][HHD]
    int i = (blockIdx.x - cpBlocks) * 256 + tid;
    const int NT = 2 * HIDD;
    if (i >= NT * HHD) return;
    int n = i % NT, k = i / NT;
    float v = (n < HIDD) ? w1[(size_t)k * HIDD + n] : w2[(size_t)k * HIDD + (n - HIDD)];
    u16 h = f2bf(v);
    u16 l = f2bf(v - bfval(h));
    wh[(size_t)n * HHD + k] = h;
    wl[(size_t)n * HHD + k] = l;
  }
}

// plain column pool (stage 2)
__global__ __launch_bounds__(256) void col_pool(const float* __restrict__ X,
                                                const int* __restrict__ perm,
                                                const float* __restrict__ scalev,
                                                int rows, int C,
                                                float* __restrict__ omax, float* __restrict__ osum) {
  int tid = threadIdx.x;
  float mx = -INFINITY, sm = 0.f;
  int rpb = (rows + gridDim.x - 1) / gridDim.x;
  int rbeg = blockIdx.x * rpb;
  int rend = min(rows, rbeg + rpb);
  for (int r = rbeg; r < rend; r++) {
    int orow = perm[r];
    float sc = scalev[orow];
    int c = tid;
    if (c < C) {
      float v = X[(size_t)orow * C + c] * sc;
      mx = fmaxf(mx, v);
      sm += v;
    }
  }
  if (rbeg < rend && tid < C) {
    atomicMaxF(&omax[tid], mx);
    atomicAdd(&osum[tid], sm);
  }
}

// ---------------- MLP head ----------------
__global__ __launch_bounds__(256) void mlp_l1(const float* __restrict__ pools,
                                              const float* __restrict__ w1,
                                              const float* __restrict__ b1,
                                              float* __restrict__ z1out) {
  __shared__ float z[1024];
  __shared__ float red[16][17];
  int t = threadIdx.x;
  for (int i = t; i < 1024; i += 256) {
    float xv = (i < 512) ? pools[i] : pools[i] * (1.f / K1N);
    float gv = (i < 512) ? pools[1024 + (i & 63)] : pools[1088 + (i & 63)] * (1.f / K2N);
    z[i] = xv + gv;
  }
  __syncthreads();
  int jl = t & 15, ch = t >> 4;
  int j = blockIdx.x * 16 + jl;
  float p = 0.f;
  for (int k = ch * 64; k < ch * 64 + 64; k++) p += z[k] * w1[(size_t)k * 512 + j];
  red[ch][jl] = p;
  __syncthreads();
  if (t < 16) {
    float s = b1[blockIdx.x * 16 + t];
    for (int c = 0; c < 16; c++) s += red[c][t];
    z1out[blockIdx.x * 16 + t] = s > 0.f ? s : 0.f;
  }
}

__global__ __launch_bounds__(256) void mlp_tail(const float* __restrict__ z1,
                                                const float* __restrict__ w2, const float* __restrict__ b2,
                                                const float* __restrict__ w3, const float* __restrict__ b3,
                                                const float* __restrict__ w4, const float* __restrict__ b4,
                                                float* __restrict__ out) {
  __shared__ float z2[256], z3[128], lg[2];
  int t = threadIdx.x;
  {
    float acc = b2[t];
    for (int k = 0; k < 512; k++) acc += z1[k] * w2[(size_t)k * 256 + t];
    z2[t] = acc > 0.f ? acc : 0.f;
  }
  __syncthreads();
  if (t < 128) {
    float acc = b3[t];
    for (int k = 0; k < 256; k++) acc += z2[k] * w3[(size_t)k * 128 + t];
    z3[t] = acc > 0.f ? acc : 0.f;
  }
  __syncthreads();
  if (t < 2) {
    float acc = b4[t];
    for (int k = 0; k < 128; k++) acc += z3[k] * w4[2 * k + t];
    lg[t] = acc;
  }
  __syncthreads();
  if (t == 0) {
    float m = fmaxf(lg[0], lg[1]);
    float e0 = __expf(lg[0] - m), e1 = __expf(lg[1] - m);
    float s = e0 + e1;
    out[0] = lg[0]; out[1] = lg[1];
    out[2] = e0 / s; out[3] = e1 / s;
  }
}

extern "C" void kernel_launch(void* const* d_in, const int* in_sizes, int n_in,
                              void* d_out, int out_size, void* d_ws, size_t ws_size,
                              hipStream_t stream) {
  const float* x       = (const float*)d_in[0];
  const int*   ei      = (const int*)d_in[1];
  const float* g1_wl   = (const float*)d_in[2];
  const float* g1_wr   = (const float*)d_in[3];
  const float* g1_att  = (const float*)d_in[4];
  const float* g1_b    = (const float*)d_in[5];
  const float* p1_w    = (const float*)d_in[6];
  const float* p1_asrc = (const float*)d_in[7];
  const float* p1_adst = (const float*)d_in[8];
  const float* p1_b    = (const float*)d_in[9];
  const float* p1_sel  = (const float*)d_in[10];
  const float* g2_wl   = (const float*)d_in[11];
  const float* g2_wr   = (const float*)d_in[12];
  const float* g2_att  = (const float*)d_in[13];
  const float* g2_b    = (const float*)d_in[14];
  const float* p2_w    = (const float*)d_in[15];
  const float* p2_asrc = (const float*)d_in[16];
  const float* p2_adst = (const float*)d_in[17];
  const float* p2_b    = (const float*)d_in[18];
  const float* p2_sel  = (const float*)d_in[19];
  const float* l1_w    = (const float*)d_in[20];
  const float* l1_b    = (const float*)d_in[21];
  const float* l2_w    = (const float*)d_in[22];
  const float* l2_b    = (const float*)d_in[23];
  const float* l3_w    = (const float*)d_in[24];
  const float* l3_b    = (const float*)d_in[25];
  const float* l4_w    = (const float*)d_in[26];
  const float* l4_b    = (const float*)d_in[27];

  const int* src = ei;
  const int* dst = ei + E_EDGES;

  if (ws_size < (size_t)33440000 * 4) return;
  float* ws  = (float*)d_ws;
  float* xl1 = ws;                 // region A: xl1b bf16 (20.5MB); later stage-2 bf16 arena
  float* xr1 = ws + 10240000;      // region B: xr1b bf16 (20.5MB); later stage-2 f32 arena
  float* h1  = ws + 20480000;      // region C: stage-1 bf16 input arena, then h1 f32
  float* aux = ws + 30720000;      // persistent small buffers

  int*   csr_s1   = (int*)aux;               // 340000
  int*   rowptr1  = (int*)(aux + 340000);    // 20001
  int*   deg1     = (int*)(aux + 360064);    // 20000 (deg -> cursor)
  int*   rank1    = (int*)(aux + 380064);    // 20000
  int*   newid1   = (int*)(aux + 400064);    // 20000
  float* xls1     = aux + 420064;            // 20000
  float* scr1     = aux + 440064;            // 20000
  float* pools    = aux + 460064;            // 1152: x1max|x1sum|g2max|g2sum
  float* x1max    = pools;
  float* x1sum    = pools + 512;
  float* g2max    = pools + 1024;
  float* g2sum    = pools + 1088;
  int*   perm1    = (int*)(aux + 461248);    // 20000
  float* z1       = aux + 481248;            // 512

  // stage-1 GEMM outputs, bf16 (regions A/B)
  u16* xl1b = (u16*)xl1;               // 10,240,000 u16
  u16* xr1b = (u16*)xr1;               // 10,240,000 u16

  // stage-1 bf16 input arena (region C; dead once gat1_fused writes h1)
  u16* ah1 = (u16*)h1;                 // 5,120,000 u16
  u16* al1 = ah1 + 5120000;            // 5,120,000
  u16* wh1 = al1 + 5120000;            // 262,144
  u16* wl1 = wh1 + 262144;             // 262,144

  // stage-2 bf16 input arena (region A; xl1b dead after gat1_fused)
  u16* ah2 = (u16*)xl1;                // 7,680,000 u16
  u16* al2 = ah2 + 7680000;            // 7,680,000
  u16* wh2 = al2 + 7680000;            // 65,536
  u16* wl2 = wh2 + 65536;              // 65,536

  float* a2 = xr1;                     // stage-2 f32 arena (region B; xr1b dead after gat1_fused)
  float* xl2      = a2;                      // 960000
  float* xr2      = a2 + 960000;             // 960000
  float* h2       = a2 + 1920000;            // 960000
  int*   csr_s2   = (int*)(a2 + 2880000);    // 335000
  int*   rowptr2  = (int*)(a2 + 3215000);    // 15001
  int*   deg2     = (int*)(a2 + 3230016);    // 15000 (deg2+rank2 contiguous)
  int*   rank2    = (int*)(a2 + 3245016);    // 15000
  int*   newid2   = (int*)(a2 + 3260016);    // 15000
  float* xls2     = a2 + 3275016;            // 15000
  float* scr2     = a2 + 3290016;            // 15000
  int*   perm2    = (int*)(a2 + 3305016);    // 15000

  dim3 b256(256);
  const int E1 = E_EDGES + N_NODES;   // 340000
  const int E2 = E_EDGES + K1N;       // 335000

  // ---- init + CSR1 ----
  init_all<<<cdiv(2 * N_NODES + 1152, 256), b256, 0, stream>>>(deg1, rank1, pools);
  deg_count<<<cdiv(E1, 256), b256, 0, stream>>>(src, dst, nullptr, deg1, N_NODES);
  scan_excl<<<1, 1024, 0, stream>>>(deg1, rowptr1, deg1, N_NODES);
  csr_scatter<<<cdiv(E1, 256), b256, 0, stream>>>(src, dst, nullptr, deg1, csr_s1, N_NODES);

  // ---- Stage 1: conv + bf16-split MFMA GEMM (bf16 outputs) + fused GAT (bf16 gather) ----
  {
    int aBlocks = cdiv((long long)N_NODES * DIN / 4, 256);
    int wBlocks = cdiv(2 * HHD * DIN, 256);
    conv_fused<<<aBlocks + wBlocks, b256, 0, stream>>>(
        x, nullptr, nullptr, ah1, al1, N_NODES, DIN, g1_wl, g1_wr, wh1, wl1, HHD, aBlocks);
  }
  gemm_bf16x3<128, true><<<dim3(2 * HHD / 128, cdiv(N_NODES, 128)), b256, 0, stream>>>(
      ah1, al1, wh1, wl1, xl1b, xr1b, N_NODES, DIN, HHD);
  gat1_fused<<<cdiv((long long)N_NODES * 64, 256), b256, 0, stream>>>(
      rowptr1, csr_s1, xl1b, xr1b, g1_att, g1_b, p1_w, h1, xls1);

  // ---- Pool 1 (topk_count also zeroes deg2+rank2, which live in dead region B) ----
  pool_score<<<cdiv(N_NODES, 256), b256, 0, stream>>>(rowptr1, csr_s1, xls1,
                                                      p1_asrc, p1_adst, p1_b, p1_sel, scr1, N_NODES);
  topk_count<<<dim3(cdiv(N_NODES, 1024), cdiv(N_NODES, TK_CHUNK)), b256, 0, stream>>>(
      scr1, rank1, N_NODES, deg2, 30000);
  topk_assign<<<cdiv(N_NODES, 256), b256, 0, stream>>>(rank1, newid1, perm1, N_NODES, K1N);
  {
    int cpBlocks = 256;
    int wBlocks = cdiv(2 * HIDD * HHD, 256);
    col_pool_conv<<<cpBlocks + wBlocks, b256, 0, stream>>>(
        h1, perm1, scr1, x1max, x1sum, ah2, al2, g2_wl, g2_wr, wh2, wl2, cpBlocks);
  }

  // ---- CSR2 + Stage 2 GEMM (f32 outputs) + fused GAT (4 nodes/wave) ----
  deg_count<<<cdiv(E2, 256), b256, 0, stream>>>(src, dst, newid1, deg2, K1N);
  scan_excl<<<1, 1024, 0, stream>>>(deg2, rowptr2, deg2, K1N);
  csr_scatter<<<cdiv(E2, 256), b256, 0, stream>>>(src, dst, newid1, deg2, csr_s2, K1N);

  gemm_bf16x3<64, false><<<dim3(2 * HIDD / 64, cdiv(K1N, 64)), b256, 0, stream>>>(
      ah2, al2, wh2, wl2, xl2, xr2, K1N, HHD, HIDD);
  gat2_fused<<<cdiv((long long)K1N * 16, 256), b256, 0, stream>>>(
      rowptr2, csr_s2, xl2, xr2, g2_att, g2_b, p2_w, h2, xls2, K1N);

  // ---- Pool 2 ----
  pool_score<<<cdiv(K1N, 256), b256, 0, stream>>>(rowptr2, csr_s2, xls2,
                                                  p2_asrc, p2_adst, p2_b, p2_sel, scr2, K1N);
  topk_count<<<dim3(cdiv(K1N, 1024), cdiv(K1N, TK_CHUNK)), b256, 0, stream>>>(
      scr2, rank2, K1N, nullptr, 0);
  topk_assign<<<cdiv(K1N, 256), b256, 0, stream>>>(rank2, newid2, perm2, K1N, K2N);
  col_pool<<<128, b256, 0, stream>>>(h2, perm2, scr2, K2N, HIDD, g2max, g2sum);

  // ---- MLP head ----
  mlp_l1<<<32, b256, 0, stream>>>(pools, l1_w, l1_b, z1);
  mlp_tail<<<1, b256, 0, stream>>>(z1, l2_w, l2_b, l3_w, l3_b, l4_w, l4_b, (float*)d_out);
}

// Round 11
// 478.958 us; speedup vs baseline: 1.1648x; 1.1648x over previous
//
#include <hip/hip_runtime.h>
#include <math.h>

#define N_NODES 20000
#define E_EDGES 320000
#define DIN     256
#define HHD     512
#define HIDD    64
#define NHEADS  8
#define K1N     15000
#define K2N     11250

typedef unsigned short u16;
typedef __attribute__((ext_vector_type(8))) short bf16x8;
typedef __attribute__((ext_vector_type(4))) float f32x4;

static inline int cdiv(long long a, long long b) { return (int)((a + b - 1) / b); }

__device__ __forceinline__ void atomicMaxF(float* addr, float val) {
  int* ai = (int*)addr;
  int old = __float_as_int(*addr);
  while (__int_as_float(old) < val) {
    int assumed = old;
    old = atomicCAS(ai, assumed, __float_as_int(val));
    if (old == assumed) break;
  }
}

__device__ __forceinline__ u16 f2bf(float x) {   // RNE f32 -> bf16 bits
  unsigned u = __float_as_uint(x);
  return (u16)((u + 0x7FFFu + ((u >> 16) & 1u)) >> 16);
}
__device__ __forceinline__ float bfval(u16 b) { return __uint_as_float(((unsigned)b) << 16); }

__device__ __forceinline__ void unpk8(uint4 u, float* v) {
  v[0] = __uint_as_float(u.x << 16); v[1] = __uint_as_float(u.x & 0xffff0000u);
  v[2] = __uint_as_float(u.y << 16); v[3] = __uint_as_float(u.y & 0xffff0000u);
  v[4] = __uint_as_float(u.z << 16); v[5] = __uint_as_float(u.z & 0xffff0000u);
  v[6] = __uint_as_float(u.w << 16); v[7] = __uint_as_float(u.w & 0xffff0000u);
}

// order-preserving float->uint key (ascending float == ascending key)
__device__ __forceinline__ unsigned fkey(float s) {
  unsigned b = __float_as_uint(s);
  return (b & 0x80000000u) ? ~b : (b | 0x80000000u);
}

// deg1=0, pools[1152]: [-inf x512, 0 x512, -inf x64, 0 x64]
__global__ void init_all(int* deg1, float* pools) {
  int i = blockIdx.x * blockDim.x + threadIdx.x;
  if (i < N_NODES) deg1[i] = 0;
  else {
    int idx = i - N_NODES;
    if (idx < 1152)
      pools[idx] = (idx < 512 || (idx >= 1024 && idx < 1088)) ? -INFINITY : 0.f;
  }
}

// ---------------- fused bf16 hi/lo split conversion (A-part + W-part in one launch) ----------------
__global__ void conv_fused(const float* __restrict__ A, const int* __restrict__ perm,
                           const float* __restrict__ scalev,
                           u16* __restrict__ ah, u16* __restrict__ al, int M, int K,
                           const float* __restrict__ w1, const float* __restrict__ w2,
                           u16* __restrict__ wh, u16* __restrict__ wl, int ncHalf,
                           int aBlocks) {
  if ((int)blockIdx.x < aBlocks) {
    long long i = (long long)blockIdx.x * blockDim.x + threadIdx.x;
    long long e0 = i * 4;
    if (e0 >= (long long)M * K) return;
    int row = (int)(e0 / K), col = (int)(e0 % K);
    int ar = perm ? perm[row] : row;
    float4 v = *(const float4*)(A + (size_t)ar * K + col);
    if (scalev) { float s = scalev[ar]; v.x *= s; v.y *= s; v.z *= s; v.w *= s; }
    u16 h0 = f2bf(v.x), h1 = f2bf(v.y), h2 = f2bf(v.z), h3 = f2bf(v.w);
    u16 l0 = f2bf(v.x - bfval(h0)), l1 = f2bf(v.y - bfval(h1));
    u16 l2 = f2bf(v.z - bfval(h2)), l3 = f2bf(v.w - bfval(h3));
    uint2 hp, lp;
    hp.x = (unsigned)h0 | ((unsigned)h1 << 16); hp.y = (unsigned)h2 | ((unsigned)h3 << 16);
    lp.x = (unsigned)l0 | ((unsigned)l1 << 16); lp.y = (unsigned)l2 | ((unsigned)l3 << 16);
    *(uint2*)(ah + e0) = hp;
    *(uint2*)(al + e0) = lp;
  } else {
    int i = (blockIdx.x - aBlocks) * blockDim.x + threadIdx.x;
    int NT = 2 * ncHalf;
    if (i >= NT * K) return;
    int n = i % NT, k = i / NT;
    float v = (n < ncHalf) ? w1[(size_t)k * ncHalf + n] : w2[(size_t)k * ncHalf + (n - ncHalf)];
    u16 h = f2bf(v);
    u16 l = f2bf(v - bfval(h));
    wh[(size_t)n * K + k] = h;
    wl[(size_t)n * K + k] = l;
  }
}

// ---------------- split-bf16 MFMA GEMM: C = A @ [W1|W2]; OUTBF: store C as bf16 ----------------
template<int BT, bool OUTBF>
__global__ __launch_bounds__(256) void gemm_bf16x3(const u16* __restrict__ ah,
                                                   const u16* __restrict__ al,
                                                   const u16* __restrict__ wh,
                                                   const u16* __restrict__ wl,
                                                   void* __restrict__ c1v,
                                                   void* __restrict__ c2v,
                                                   int M, int K, int ncHalf) {
  constexpr int F = BT / 32;
  __shared__ u16 Ah[BT][40], Al[BT][40], Bh[BT][40], Bl[BT][40];
  int tid = threadIdx.x;
  int lane = tid & 63, wid = tid >> 6;
  int wr = (wid >> 1) * (BT / 2), wc = (wid & 1) * (BT / 2);
  int brow = blockIdx.y * BT, bcol = blockIdx.x * BT;
  int fr = lane & 15, kg = lane >> 4;
  f32x4 acc[F][F];
#pragma unroll
  for (int i = 0; i < F; i++)
#pragma unroll
    for (int j = 0; j < F; j++) acc[i][j] = (f32x4){0.f, 0.f, 0.f, 0.f};

  for (int k0 = 0; k0 < K; k0 += 32) {
    constexpr int ITER = (BT * 32) / (256 * 8);
#pragma unroll
    for (int i = 0; i < ITER; i++) {
      int pos = tid + i * 256;
      int row = pos >> 2;
      int kc = (pos & 3) * 8;
      int gr = brow + row;
      float4 z = make_float4(0.f, 0.f, 0.f, 0.f);
      float4 vah = (gr < M) ? *(const float4*)(ah + (size_t)gr * K + k0 + kc) : z;
      float4 val = (gr < M) ? *(const float4*)(al + (size_t)gr * K + k0 + kc) : z;
      *(float4*)(&Ah[row][kc]) = vah;
      *(float4*)(&Al[row][kc]) = val;
      int gn = bcol + row;
      *(float4*)(&Bh[row][kc]) = *(const float4*)(wh + (size_t)gn * K + k0 + kc);
      *(float4*)(&Bl[row][kc]) = *(const float4*)(wl + (size_t)gn * K + k0 + kc);
    }
    __syncthreads();
    bf16x8 fa_h[F], fa_l[F], fb_h[F], fb_l[F];
#pragma unroll
    for (int t = 0; t < F; t++) {
      fa_h[t] = *(const bf16x8*)(&Ah[wr + t * 16 + fr][kg * 8]);
      fa_l[t] = *(const bf16x8*)(&Al[wr + t * 16 + fr][kg * 8]);
      fb_h[t] = *(const bf16x8*)(&Bh[wc + t * 16 + fr][kg * 8]);
      fb_l[t] = *(const bf16x8*)(&Bl[wc + t * 16 + fr][kg * 8]);
    }
#pragma unroll
    for (int i = 0; i < F; i++)
#pragma unroll
      for (int j = 0; j < F; j++) {
        acc[i][j] = __builtin_amdgcn_mfma_f32_16x16x32_bf16(fa_h[i], fb_h[j], acc[i][j], 0, 0, 0);
        acc[i][j] = __builtin_amdgcn_mfma_f32_16x16x32_bf16(fa_h[i], fb_l[j], acc[i][j], 0, 0, 0);
        acc[i][j] = __builtin_amdgcn_mfma_f32_16x16x32_bf16(fa_l[i], fb_h[j], acc[i][j], 0, 0, 0);
      }
    __syncthreads();
  }
#pragma unroll
  for (int i = 0; i < F; i++) {
    int r0 = brow + wr + i * 16 + kg * 4;
#pragma unroll
    for (int j = 0; j < F; j++) {
      int cg = bcol + wc + j * 16 + fr;
      bool first = (cg < ncHalf);
      int cc = first ? cg : cg - ncHalf;
#pragma unroll
      for (int r = 0; r < 4; r++) {
        int gr = r0 + r;
        if (gr < M) {
          if (OUTBF) {
            u16* cp = first ? (u16*)c1v : (u16*)c2v;
            cp[(size_t)gr * ncHalf + cc] = f2bf(acc[i][j][r]);
          } else {
            float* cp = first ? (float*)c1v : (float*)c2v;
            cp[(size_t)gr * ncHalf + cc] = acc[i][j][r];
          }
        }
      }
    }
  }
}

// ---------------- CSR construction (stores mapped source id directly) ----------------
__global__ void deg_count(const int* __restrict__ src, const int* __restrict__ dst,
                          const int* __restrict__ newid, int* __restrict__ deg,
                          int nloops) {
  int i = blockIdx.x * blockDim.x + threadIdx.x;
  if (i >= E_EDGES + nloops) return;
  int d;
  if (i < E_EDGES) {
    if (newid) {
      int s = newid[src[i]]; d = newid[dst[i]];
      if (s < 0 || d < 0) return;
    } else d = dst[i];
  } else d = i - E_EDGES;
  atomicAdd(&deg[d], 1);
}

// shuffle-based single-block exclusive scan; cursor may alias deg.
__global__ __launch_bounds__(1024) void scan_excl(const int* deg, int* rowptr,
                                                  int* cursor, int n) {
  __shared__ int wsum[16];
  __shared__ int carry;
  int tid = threadIdx.x, lane = tid & 63, wid = tid >> 6;
  if (tid == 0) { carry = 0; rowptr[0] = 0; }
  __syncthreads();
  for (int base = 0; base < n; base += 1024) {
    int v = (base + tid < n) ? deg[base + tid] : 0;
    int s = v;
#pragma unroll
    for (int off = 1; off < 64; off <<= 1) {
      int t = __shfl_up(s, off);
      if (lane >= off) s += t;
    }
    if (lane == 63) wsum[wid] = s;
    __syncthreads();
    if (wid == 0) {
      int w = (lane < 16) ? wsum[lane] : 0;
#pragma unroll
      for (int off = 1; off < 16; off <<= 1) {
        int t = __shfl_up(w, off);
        if (lane >= off) w += t;
      }
      if (lane < 16) wsum[lane] = w;
    }
    __syncthreads();
    int incl = s + (wid > 0 ? wsum[wid - 1] : 0) + carry;
    if (base + tid < n) { rowptr[base + tid + 1] = incl; cursor[base + tid] = incl - v; }
    __syncthreads();
    if (tid == 1023) carry = incl;
    __syncthreads();
  }
}

__global__ void csr_scatter(const int* __restrict__ src, const int* __restrict__ dst,
                            const int* __restrict__ newid, int* __restrict__ cursor,
                            int* __restrict__ csr_s, int nloops) {
  int i = blockIdx.x * blockDim.x + threadIdx.x;
  if (i >= E_EDGES + nloops) return;
  int s, d;
  if (i < E_EDGES) {
    s = src[i]; d = dst[i];
    if (newid) {
      s = newid[s]; d = newid[d];
      if (s < 0 || d < 0) return;
    }
  } else s = d = i - E_EDGES;
  int pos = atomicAdd(&cursor[d], 1);
  csr_s[pos] = s;
}

// ---------------- Stage 1 fused GAT: 1 wave/node, bf16 gather, 4-deep prefetch ----------------
__global__ __launch_bounds__(256) void gat1_fused(const int* __restrict__ rowptr,
                                                  const int* __restrict__ csr_s,
                                                  const u16* __restrict__ xlb,
                                                  const u16* __restrict__ xrb,
                                                  const float* __restrict__ att,
                                                  const float* __restrict__ bias,
                                                  const float* __restrict__ pw,
                                                  float* __restrict__ out,
                                                  float* __restrict__ xls) {
  int lane = threadIdx.x & 63;
  long long t = (long long)blockIdx.x * blockDim.x + threadIdx.x;
  int d = (int)(t >> 6);
  if (d >= N_NODES) return;
  int base = lane * 8;                       // 8 cols/lane, head = lane>>3
  float4 a0 = *(const float4*)(att + base);
  float4 a1 = *(const float4*)(att + base + 4);
  float r[8];
  unpk8(*(const uint4*)(xrb + (size_t)d * HHD + base), r);
  float m = -INFINITY, den = 0.f;
  float acc[8] = {0.f, 0.f, 0.f, 0.f, 0.f, 0.f, 0.f, 0.f};
  int b0 = rowptr[d];
  int cnt = rowptr[d + 1] - b0;
  const int* sp = csr_s + b0;

  auto online = [&](uint4 u) {
    float v[8];
    unpk8(u, v);
    float p, tv;
    tv = v[0] + r[0]; tv = tv > 0.f ? tv : 0.2f * tv; p  = tv * a0.x;
    tv = v[1] + r[1]; tv = tv > 0.f ? tv : 0.2f * tv; p += tv * a0.y;
    tv = v[2] + r[2]; tv = tv > 0.f ? tv : 0.2f * tv; p += tv * a0.z;
    tv = v[3] + r[3]; tv = tv > 0.f ? tv : 0.2f * tv; p += tv * a0.w;
    tv = v[4] + r[4]; tv = tv > 0.f ? tv : 0.2f * tv; p += tv * a1.x;
    tv = v[5] + r[5]; tv = tv > 0.f ? tv : 0.2f * tv; p += tv * a1.y;
    tv = v[6] + r[6]; tv = tv > 0.f ? tv : 0.2f * tv; p += tv * a1.z;
    tv = v[7] + r[7]; tv = tv > 0.f ? tv : 0.2f * tv; p += tv * a1.w;
    p += __shfl_xor(p, 1); p += __shfl_xor(p, 2); p += __shfl_xor(p, 4);
    float nm = fmaxf(m, p);
    float w  = __expf(p - nm);
    float sc = __expf(m - nm);
    den = den * sc + w;
#pragma unroll
    for (int k = 0; k < 8; k++) acc[k] = acc[k] * sc + w * v[k];
    m = nm;
  };

  uint4 zz = make_uint4(0u, 0u, 0u, 0u);
  uint4 A = *(const uint4*)(xlb + (size_t)sp[0] * HHD + base);
  uint4 B = (cnt > 1) ? *(const uint4*)(xlb + (size_t)sp[1] * HHD + base) : zz;
  uint4 C = (cnt > 2) ? *(const uint4*)(xlb + (size_t)sp[2] * HHD + base) : zz;
  uint4 D = (cnt > 3) ? *(const uint4*)(xlb + (size_t)sp[3] * HHD + base) : zz;
  int j = 0;
  for (; j + 4 <= cnt; j += 4) {
    uint4 u = A;
    if (j + 4 < cnt) A = *(const uint4*)(xlb + (size_t)sp[j + 4] * HHD + base);
    online(u);
    u = B;
    if (j + 5 < cnt) B = *(const uint4*)(xlb + (size_t)sp[j + 5] * HHD + base);
    online(u);
    u = C;
    if (j + 6 < cnt) C = *(const uint4*)(xlb + (size_t)sp[j + 6] * HHD + base);
    online(u);
    u = D;
    if (j + 7 < cnt) D = *(const uint4*)(xlb + (size_t)sp[j + 7] * HHD + base);
    online(u);
  }
  if (j < cnt) {
    online(A);
    if (j + 1 < cnt) {
      online(B);
      if (j + 2 < cnt) online(C);
    }
  }

  float inv = 1.f / den;
  float4 b0v = *(const float4*)(bias + base);
  float4 b1v = *(const float4*)(bias + base + 4);
  float o[8];
  o[0] = acc[0] * inv + b0v.x; o[1] = acc[1] * inv + b0v.y;
  o[2] = acc[2] * inv + b0v.z; o[3] = acc[3] * inv + b0v.w;
  o[4] = acc[4] * inv + b1v.x; o[5] = acc[5] * inv + b1v.y;
  o[6] = acc[6] * inv + b1v.z; o[7] = acc[7] * inv + b1v.w;
#pragma unroll
  for (int k = 0; k < 8; k++) o[k] = o[k] > 0.f ? o[k] : 0.f;
  float* op = out + (size_t)d * HHD + base;
  *(float4*)(op)     = make_float4(o[0], o[1], o[2], o[3]);
  *(float4*)(op + 4) = make_float4(o[4], o[5], o[6], o[7]);
  float4 w0 = *(const float4*)(pw + base);
  float4 w1 = *(const float4*)(pw + base + 4);
  float sdot = o[0]*w0.x + o[1]*w0.y + o[2]*w0.z + o[3]*w0.w
             + o[4]*w1.x + o[5]*w1.y + o[6]*w1.z + o[7]*w1.w;
#pragma unroll
  for (int off = 32; off > 0; off >>= 1) sdot += __shfl_xor(sdot, off);
  if (lane == 0) xls[d] = sdot;
}

// ---------------- Stage 2 fused GAT: 4 nodes per wave (one per 16-lane group) ----------------
__global__ __launch_bounds__(256) void gat2_fused(const int* __restrict__ rowptr,
                                                  const int* __restrict__ csr_s,
                                                  const float* __restrict__ xl,
                                                  const float* __restrict__ xr,
                                                  const float* __restrict__ att,
                                                  const float* __restrict__ bias,
                                                  const float* __restrict__ pw,
                                                  float* __restrict__ out,
                                                  float* __restrict__ xls, int n) {
  int lane = threadIdx.x & 63;
  int grp = lane >> 4, li = lane & 15;
  long long t = (long long)blockIdx.x * blockDim.x + threadIdx.x;
  int wv = (int)(t >> 6);
  int d = wv * 4 + grp;
  if (d >= n) return;
  int c0 = li * 4;
  float4 av = *(const float4*)(att + c0);
  float4 rv = *(const float4*)(xr + (size_t)d * HIDD + c0);
  float m = -INFINITY, den = 0.f;
  float4 acc = make_float4(0.f, 0.f, 0.f, 0.f);
  int b0 = rowptr[d];
  int cnt = rowptr[d + 1] - b0;
  const int* sp = csr_s + b0;

  auto online = [&](float4 v) {
    float p, tv;
    tv = v.x + rv.x; tv = tv > 0.f ? tv : 0.2f * tv; p  = tv * av.x;
    tv = v.y + rv.y; tv = tv > 0.f ? tv : 0.2f * tv; p += tv * av.y;
    tv = v.z + rv.z; tv = tv > 0.f ? tv : 0.2f * tv; p += tv * av.z;
    tv = v.w + rv.w; tv = tv > 0.f ? tv : 0.2f * tv; p += tv * av.w;
    p += __shfl_xor(p, 1); p += __shfl_xor(p, 2); p += __shfl_xor(p, 4); p += __shfl_xor(p, 8);
    float nm = fmaxf(m, p);
    float w  = __expf(p - nm);
    float sc = __expf(m - nm);
    den = den * sc + w;
    acc.x = acc.x * sc + w * v.x;
    acc.y = acc.y * sc + w * v.y;
    acc.z = acc.z * sc + w * v.z;
    acc.w = acc.w * sc + w * v.w;
    m = nm;
  };

  float4 zz = make_float4(0.f, 0.f, 0.f, 0.f);
  float4 A = *(const float4*)(xl + (size_t)sp[0] * HIDD + c0);
  float4 B = (cnt > 1) ? *(const float4*)(xl + (size_t)sp[1] * HIDD + c0) : zz;
  int j = 0;
  for (; j + 2 <= cnt; j += 2) {
    float4 v = A;
    if (j + 2 < cnt) A = *(const float4*)(xl + (size_t)sp[j + 2] * HIDD + c0);
    online(v);
    v = B;
    if (j + 3 < cnt) B = *(const float4*)(xl + (size_t)sp[j + 3] * HIDD + c0);
    online(v);
  }
  if (j < cnt) online(A);

  float inv = 1.f / den;
  float4 bv = *(const float4*)(bias + c0);
  float4 o;
  o.x = acc.x * inv + bv.x; o.y = acc.y * inv + bv.y;
  o.z = acc.z * inv + bv.z; o.w = acc.w * inv + bv.w;
  o.x = o.x > 0.f ? o.x : 0.f; o.y = o.y > 0.f ? o.y : 0.f;
  o.z = o.z > 0.f ? o.z : 0.f; o.w = o.w > 0.f ? o.w : 0.f;
  *(float4*)(out + (size_t)d * HIDD + c0) = o;
  float4 wv4 = *(const float4*)(pw + c0);
  float sdot = o.x * wv4.x + o.y * wv4.y + o.z * wv4.z + o.w * wv4.w;
  sdot += __shfl_xor(sdot, 1); sdot += __shfl_xor(sdot, 2);
  sdot += __shfl_xor(sdot, 4); sdot += __shfl_xor(sdot, 8);
  if (li == 0) xls[d] = sdot;
}

// ---------------- pool scoring: online softmax + tanh, 4-deep prefetch ----------------
__global__ __launch_bounds__(256) void pool_score(const int* __restrict__ rowptr,
                                                  const int* __restrict__ csr_s,
                                                  const float* __restrict__ xls,
                                                  const float* __restrict__ asrc,
                                                  const float* __restrict__ adst,
                                                  const float* __restrict__ bias,
                                                  const float* __restrict__ sel,
                                                  float* __restrict__ score, int n) {
  int d = blockIdx.x * blockDim.x + threadIdx.x;
  if (d >= n) return;
  float as = asrc[0], ad = adst[0];
  float ar = xls[d] * ad;
  int b0 = rowptr[d];
  int cnt = rowptr[d + 1] - b0;
  const int* sp = csr_s + b0;
  float m = -INFINITY, den = 0.f, num = 0.f;
  auto upd = [&](float xs) {
    float e = xs * as + ar;
    e = e > 0.f ? e : 0.2f * e;
    float nm = fmaxf(m, e);
    float scv = __expf(m - nm);
    float ex = __expf(e - nm);
    den = den * scv + ex;
    num = num * scv + ex * xs;
    m = nm;
  };
  float xA = xls[sp[0]];
  float xB = (cnt > 1) ? xls[sp[1]] : 0.f;
  float xC = (cnt > 2) ? xls[sp[2]] : 0.f;
  float xD = (cnt > 3) ? xls[sp[3]] : 0.f;
  int j = 0;
  for (; j + 4 <= cnt; j += 4) {
    float x1 = xA;
    if (j + 4 < cnt) xA = xls[sp[j + 4]];
    upd(x1);
    float x2 = xB;
    if (j + 5 < cnt) xB = xls[sp[j + 5]];
    upd(x2);
    float x3 = xC;
    if (j + 6 < cnt) xC = xls[sp[j + 6]];
    upd(x3);
    float x4 = xD;
    if (j + 7 < cnt) xD = xls[sp[j + 7]];
    upd(x4);
  }
  if (j < cnt) {
    upd(xA);
    if (j + 1 < cnt) {
      upd(xB);
      if (j + 2 < cnt) upd(xC);
    }
  }
  float attn = num / den + bias[0];
  float sv = sel[0];
  score[d] = tanhf(attn * sv / fabsf(sv));
}

// ---------------- exact top-k via single-block radix select (O(N)) ----------------
// Finds k-th largest key threshold U (3 passes: 11+11+10 bits), then one dual-prefix
// pass assigns newid[i] = #selected-before-i (index-ordered; ties at U taken by
// smallest index, matching jax.lax.top_k's selected SET; ordering is free by
// permutation invariance). Optionally zero-fills zbuf.
__global__ __launch_bounds__(1024) void tk_topk(const float* __restrict__ score, int n, int k,
                                                int* __restrict__ newid, int* __restrict__ perm,
                                                int* __restrict__ zbuf, int zn) {
  __shared__ unsigned bins[2048];
  __shared__ unsigned wsum[16];
  __shared__ unsigned sb[4];
  int tid = threadIdx.x, lane = tid & 63, wid = tid >> 6;

  for (int i = tid; i < zn; i += 1024) zbuf[i] = 0;

  unsigned pref = 0;
  unsigned kneed = (unsigned)k;

  for (int level = 0; level < 3; level++) {
    const int shift = (level == 0) ? 21 : (level == 1) ? 10 : 0;
    const unsigned mask = (level == 2) ? 1023u : 2047u;
    for (int b = tid; b < 2048; b += 1024) bins[b] = 0;
    __syncthreads();
    for (int i = tid; i < n; i += 1024) {
      unsigned key = fkey(score[i]);
      bool match = (level == 0) ? true
                 : (level == 1) ? ((key >> 21) == pref)
                                : ((key >> 10) == pref);
      if (match) atomicAdd(&bins[(key >> shift) & mask], 1u);
    }
    __syncthreads();
    // inclusive prefix over 2048 bins; thread owns bins[2t], bins[2t+1]
    unsigned c0 = bins[2 * tid], c1 = bins[2 * tid + 1];
    unsigned v = c0 + c1;
    unsigned s = v;
#pragma unroll
    for (int off = 1; off < 64; off <<= 1) {
      unsigned t2 = __shfl_up(s, off);
      if (lane >= off) s += t2;
    }
    if (lane == 63) wsum[wid] = s;
    __syncthreads();
    if (wid == 0) {
      unsigned w = (lane < 16) ? wsum[lane] : 0;
#pragma unroll
      for (int off = 1; off < 16; off <<= 1) {
        unsigned t2 = __shfl_up(w, off);
        if (lane >= off) w += t2;
      }
      if (lane < 16) wsum[lane] = w;
    }
    __syncthreads();
    unsigned incl = s + (wid > 0 ? wsum[wid - 1] : 0);
    unsigned excl = incl - v;
    if (tid == 1023) sb[0] = incl;           // TOT (matched count)
    __syncthreads();
    unsigned TOT = sb[0];
    unsigned target = TOT - kneed;           // find b: IP(b-1) <= target < IP(b)
    unsigned ip0 = excl + c0;
    unsigned ip1 = ip0 + c1;
    if (excl <= target && target < ip0) { sb[1] = 2u * tid;     sb[2] = TOT - ip0; }
    if (ip0  <= target && target < ip1) { sb[1] = 2u * tid + 1; sb[2] = TOT - ip1; }
    __syncthreads();
    pref = (pref << ((level == 2) ? 10 : 11)) | sb[1];
    kneed -= sb[2];
    __syncthreads();
  }
  const unsigned U = pref, rem = kneed;

  // selection + id assignment: dual exclusive prefix over (gt, tie), index order
  unsigned carry = 0;
  for (int base = 0; base < n; base += 1024) {
    int i = base + tid;
    bool valid = i < n;
    unsigned key = valid ? fkey(score[i]) : 0u;
    unsigned gt  = (valid && key >  U) ? 1u : 0u;
    unsigned tie = (valid && key == U) ? 1u : 0u;
    unsigned v = gt | (tie << 16);           // counts < 65536, no cross-carry
    unsigned s = v;
#pragma unroll
    for (int off = 1; off < 64; off <<= 1) {
      unsigned t2 = __shfl_up(s, off);
      if (lane >= off) s += t2;
    }
    if (lane == 63) wsum[wid] = s;
    __syncthreads();
    if (wid == 0) {
      unsigned w = (lane < 16) ? wsum[lane] : 0;
#pragma unroll
      for (int off = 1; off < 16; off <<= 1) {
        unsigned t2 = __shfl_up(w, off);
        if (lane >= off) w += t2;
      }
      if (lane < 16) wsum[lane] = w;
    }
    __syncthreads();
    unsigned incl = s + (wid > 0 ? wsum[wid - 1] : 0);
    unsigned pfx = (incl - v) + carry;
    unsigned gtpfx = pfx & 0xFFFFu, tiepfx = pfx >> 16;
    unsigned tsel = (tiepfx < rem) ? tiepfx : rem;
    bool selq = gt || (tie && tiepfx < rem);
    unsigned id = gtpfx + tsel;
    if (valid) {
      newid[i] = selq ? (int)id : -1;
      if (selq) perm[id] = i;
    }
    if (tid == 1023) sb[0] = incl + carry;
    __syncthreads();
    carry = sb[0];
    __syncthreads();
  }
}

// stage-1 column pool fused with stage-2 A-conversion (+W2 conversion in extra blocks)
__global__ __launch_bounds__(256) void col_pool_conv(const float* __restrict__ X,
                                                     const int* __restrict__ perm,
                                                     const float* __restrict__ scalev,
                                                     float* __restrict__ omax,
                                                     float* __restrict__ osum,
                                                     u16* __restrict__ ah, u16* __restrict__ al,
                                                     const float* __restrict__ w1,
                                                     const float* __restrict__ w2,
                                                     u16* __restrict__ wh, u16* __restrict__ wl,
                                                     int cpBlocks) {
  int tid = threadIdx.x;
  if ((int)blockIdx.x < cpBlocks) {
    float mx[2] = {-INFINITY, -INFINITY};
    float sm[2] = {0.f, 0.f};
    int rpb = (K1N + cpBlocks - 1) / cpBlocks;
    int rbeg = blockIdx.x * rpb;
    int rend = min(K1N, rbeg + rpb);
    for (int r = rbeg; r < rend; r++) {
      int orow = perm[r];
      float sc = scalev[orow];
      const float* row = X + (size_t)orow * HHD;
#pragma unroll
      for (int sg = 0; sg < 2; sg++) {
        int c = sg * 256 + tid;
        float v = row[c] * sc;
        mx[sg] = fmaxf(mx[sg], v);
        sm[sg] += v;
        u16 h = f2bf(v);
        u16 l = f2bf(v - bfval(h));
        ah[(size_t)r * HHD + c] = h;
        al[(size_t)r * HHD + c] = l;
      }
    }
    if (rbeg < rend) {
#pragma unroll
      for (int sg = 0; sg < 2; sg++) {
        int c = sg * 256 + tid;
        atomicMaxF(&omax[c], mx[sg]);
        atomicAdd(&osum[c], sm[sg]);
      }
    }
  } else {
    int i = (blockIdx.x - cpBlocks) * 256 + tid;
    const int NT = 2 * HIDD;
    if (i >= NT * HHD) return;
    int n = i % NT, k = i / NT;
    float v = (n < HIDD) ? w1[(size_t)k * HIDD + n] : w2[(size_t)k * HIDD + (n - HIDD)];
    u16 h = f2bf(v);
    u16 l = f2bf(v - bfval(h));
    wh[(size_t)n * HHD + k] = h;
    wl[(size_t)n * HHD + k] = l;
  }
}

// plain column pool (stage 2)
__global__ __launch_bounds__(256) void col_pool(const float* __restrict__ X,
                                                const int* __restrict__ perm,
                                                const float* __restrict__ scalev,
                                                int rows, int C,
                                                float* __restrict__ omax, float* __restrict__ osum) {
  int tid = threadIdx.x;
  float mx = -INFINITY, sm = 0.f;
  int rpb = (rows + gridDim.x - 1) / gridDim.x;
  int rbeg = blockIdx.x * rpb;
  int rend = min(rows, rbeg + rpb);
  for (int r = rbeg; r < rend; r++) {
    int orow = perm[r];
    float sc = scalev[orow];
    int c = tid;
    if (c < C) {
      float v = X[(size_t)orow * C + c] * sc;
      mx = fmaxf(mx, v);
      sm += v;
    }
  }
  if (rbeg < rend && tid < C) {
    atomicMaxF(&omax[tid], mx);
    atomicAdd(&osum[tid], sm);
  }
}

// ---------------- MLP head ----------------
__global__ __launch_bounds__(256) void mlp_l1(const float* __restrict__ pools,
                                              const float* __restrict__ w1,
                                              const float* __restrict__ b1,
                                              float* __restrict__ z1out) {
  __shared__ float z[1024];
  __shared__ float red[16][17];
  int t = threadIdx.x;
  for (int i = t; i < 1024; i += 256) {
    float xv = (i < 512) ? pools[i] : pools[i] * (1.f / K1N);
    float gv = (i < 512) ? pools[1024 + (i & 63)] : pools[1088 + (i & 63)] * (1.f / K2N);
    z[i] = xv + gv;
  }
  __syncthreads();
  int jl = t & 15, ch = t >> 4;
  int j = blockIdx.x * 16 + jl;
  float p = 0.f;
  for (int k = ch * 64; k < ch * 64 + 64; k++) p += z[k] * w1[(size_t)k * 512 + j];
  red[ch][jl] = p;
  __syncthreads();
  if (t < 16) {
    float s = b1[blockIdx.x * 16 + t];
    for (int c = 0; c < 16; c++) s += red[c][t];
    z1out[blockIdx.x * 16 + t] = s > 0.f ? s : 0.f;
  }
}

template<int NIN>
__global__ __launch_bounds__(256) void mlp_layer(const float* __restrict__ in,
                                                 const float* __restrict__ w,
                                                 const float* __restrict__ b,
                                                 float* __restrict__ out, int nout) {
  __shared__ float red[16][17];
  int t = threadIdx.x;
  int jl = t & 15, ch = t >> 4;
  int j = blockIdx.x * 16 + jl;
  constexpr int CH = NIN / 16;
  float p = 0.f;
  for (int k = ch * CH; k < (ch + 1) * CH; k++) p += in[k] * w[(size_t)k * nout + j];
  red[ch][jl] = p;
  __syncthreads();
  if (t < 16) {
    float s = b[blockIdx.x * 16 + t];
    for (int c = 0; c < 16; c++) s += red[c][t];
    out[blockIdx.x * 16 + t] = s > 0.f ? s : 0.f;
  }
}

__global__ __launch_bounds__(128) void mlp_final(const float* __restrict__ z3,
                                                 const float* __restrict__ w4,
                                                 const float* __restrict__ b4,
                                                 float* __restrict__ out) {
  int t = threadIdx.x;
  float v = z3[t];
  float p0 = v * w4[2 * t], p1 = v * w4[2 * t + 1];
#pragma unroll
  for (int off = 32; off > 0; off >>= 1) {
    p0 += __shfl_xor(p0, off);
    p1 += __shfl_xor(p1, off);
  }
  __shared__ float s0[2], s1[2];
  if ((t & 63) == 0) { s0[t >> 6] = p0; s1[t >> 6] = p1; }
  __syncthreads();
  if (t == 0) {
    float l0 = s0[0] + s0[1] + b4[0], l1 = s1[0] + s1[1] + b4[1];
    float m = fmaxf(l0, l1);
    float e0 = __expf(l0 - m), e1 = __expf(l1 - m);
    float s = e0 + e1;
    out[0] = l0; out[1] = l1;
    out[2] = e0 / s; out[3] = e1 / s;
  }
}

extern "C" void kernel_launch(void* const* d_in, const int* in_sizes, int n_in,
                              void* d_out, int out_size, void* d_ws, size_t ws_size,
                              hipStream_t stream) {
  const float* x       = (const float*)d_in[0];
  const int*   ei      = (const int*)d_in[1];
  const float* g1_wl   = (const float*)d_in[2];
  const float* g1_wr   = (const float*)d_in[3];
  const float* g1_att  = (const float*)d_in[4];
  const float* g1_b    = (const float*)d_in[5];
  const float* p1_w    = (const float*)d_in[6];
  const float* p1_asrc = (const float*)d_in[7];
  const float* p1_adst = (const float*)d_in[8];
  const float* p1_b    = (const float*)d_in[9];
  const float* p1_sel  = (const float*)d_in[10];
  const float* g2_wl   = (const float*)d_in[11];
  const float* g2_wr   = (const float*)d_in[12];
  const float* g2_att  = (const float*)d_in[13];
  const float* g2_b    = (const float*)d_in[14];
  const float* p2_w    = (const float*)d_in[15];
  const float* p2_asrc = (const float*)d_in[16];
  const float* p2_adst = (const float*)d_in[17];
  const float* p2_b    = (const float*)d_in[18];
  const float* p2_sel  = (const float*)d_in[19];
  const float* l1_w    = (const float*)d_in[20];
  const float* l1_b    = (const float*)d_in[21];
  const float* l2_w    = (const float*)d_in[22];
  const float* l2_b    = (const float*)d_in[23];
  const float* l3_w    = (const float*)d_in[24];
  const float* l3_b    = (const float*)d_in[25];
  const float* l4_w    = (const float*)d_in[26];
  const float* l4_b    = (const float*)d_in[27];

  const int* src = ei;
  const int* dst = ei + E_EDGES;

  if (ws_size < (size_t)33440000 * 4) return;
  float* ws  = (float*)d_ws;
  float* xl1 = ws;                 // region A: xl1b bf16; later stage-2 bf16 arena
  float* xr1 = ws + 10240000;      // region B: xr1b bf16; later stage-2 f32 arena
  float* h1  = ws + 20480000;      // region C: stage-1 bf16 input arena, then h1 f32
  float* aux = ws + 30720000;      // persistent small buffers

  int*   csr_s1   = (int*)aux;               // 340000
  int*   rowptr1  = (int*)(aux + 340000);    // 20001
  int*   deg1     = (int*)(aux + 360064);    // 20000 (deg -> cursor)
  int*   newid1   = (int*)(aux + 400064);    // 20000
  float* xls1     = aux + 420064;            // 20000
  float* scr1     = aux + 440064;            // 20000
  float* pools    = aux + 460064;            // 1152: x1max|x1sum|g2max|g2sum
  float* x1max    = pools;
  float* x1sum    = pools + 512;
  float* g2max    = pools + 1024;
  float* g2sum    = pools + 1088;
  int*   perm1    = (int*)(aux + 461248);    // 20000
  float* z1       = aux + 481248;            // 512
  float* z2       = aux + 481760;            // 256
  float* z3       = aux + 482016;            // 128

  // stage-1 GEMM outputs, bf16 (regions A/B)
  u16* xl1b = (u16*)xl1;
  u16* xr1b = (u16*)xr1;

  // stage-1 bf16 input arena (region C; dead once gat1_fused writes h1)
  u16* ah1 = (u16*)h1;
  u16* al1 = ah1 + 5120000;
  u16* wh1 = al1 + 5120000;
  u16* wl1 = wh1 + 262144;

  // stage-2 bf16 input arena (region A; xl1b dead after gat1_fused)
  u16* ah2 = (u16*)xl1;
  u16* al2 = ah2 + 7680000;
  u16* wh2 = al2 + 7680000;
  u16* wl2 = wh2 + 65536;

  float* a2 = xr1;                     // stage-2 f32 arena (region B)
  float* xl2      = a2;                      // 960000
  float* xr2      = a2 + 960000;             // 960000
  float* h2       = a2 + 1920000;            // 960000
  int*   csr_s2   = (int*)(a2 + 2880000);    // 335000
  int*   rowptr2  = (int*)(a2 + 3215000);    // 15001
  int*   deg2     = (int*)(a2 + 3230016);    // 15000
  int*   newid2   = (int*)(a2 + 3260016);    // 15000
  float* xls2     = a2 + 3275016;            // 15000
  float* scr2     = a2 + 3290016;            // 15000
  int*   perm2    = (int*)(a2 + 3305016);    // 15000

  dim3 b256(256);
  const int E1 = E_EDGES + N_NODES;   // 340000
  const int E2 = E_EDGES + K1N;       // 335000

  // ---- init + CSR1 ----
  init_all<<<cdiv(N_NODES + 1152, 256), b256, 0, stream>>>(deg1, pools);
  deg_count<<<cdiv(E1, 256), b256, 0, stream>>>(src, dst, nullptr, deg1, N_NODES);
  scan_excl<<<1, 1024, 0, stream>>>(deg1, rowptr1, deg1, N_NODES);
  csr_scatter<<<cdiv(E1, 256), b256, 0, stream>>>(src, dst, nullptr, deg1, csr_s1, N_NODES);

  // ---- Stage 1: conv + bf16-split MFMA GEMM (bf16 outputs) + fused GAT (bf16 gather) ----
  {
    int aBlocks = cdiv((long long)N_NODES * DIN / 4, 256);
    int wBlocks = cdiv(2 * HHD * DIN, 256);
    conv_fused<<<aBlocks + wBlocks, b256, 0, stream>>>(
        x, nullptr, nullptr, ah1, al1, N_NODES, DIN, g1_wl, g1_wr, wh1, wl1, HHD, aBlocks);
  }
  gemm_bf16x3<128, true><<<dim3(2 * HHD / 128, cdiv(N_NODES, 128)), b256, 0, stream>>>(
      ah1, al1, wh1, wl1, xl1b, xr1b, N_NODES, DIN, HHD);
  gat1_fused<<<cdiv((long long)N_NODES * 64, 256), b256, 0, stream>>>(
      rowptr1, csr_s1, xl1b, xr1b, g1_att, g1_b, p1_w, h1, xls1);

  // ---- Pool 1: score -> radix-select top-k (also zeroes deg2 in dead region B) ----
  pool_score<<<cdiv(N_NODES, 256), b256, 0, stream>>>(rowptr1, csr_s1, xls1,
                                                      p1_asrc, p1_adst, p1_b, p1_sel, scr1, N_NODES);
  tk_topk<<<1, 1024, 0, stream>>>(scr1, N_NODES, K1N, newid1, perm1, deg2, 15000);
  {
    int cpBlocks = 256;
    int wBlocks = cdiv(2 * HIDD * HHD, 256);
    col_pool_conv<<<cpBlocks + wBlocks, b256, 0, stream>>>(
        h1, perm1, scr1, x1max, x1sum, ah2, al2, g2_wl, g2_wr, wh2, wl2, cpBlocks);
  }

  // ---- CSR2 + Stage 2 GEMM (f32 outputs) + fused GAT (4 nodes/wave) ----
  deg_count<<<cdiv(E2, 256), b256, 0, stream>>>(src, dst, newid1, deg2, K1N);
  scan_excl<<<1, 1024, 0, stream>>>(deg2, rowptr2, deg2, K1N);
  csr_scatter<<<cdiv(E2, 256), b256, 0, stream>>>(src, dst, newid1, deg2, csr_s2, K1N);

  gemm_bf16x3<64, false><<<dim3(2 * HIDD / 64, cdiv(K1N, 64)), b256, 0, stream>>>(
      ah2, al2, wh2, wl2, xl2, xr2, K1N, HHD, HIDD);
  gat2_fused<<<cdiv((long long)K1N * 16, 256), b256, 0, stream>>>(
      rowptr2, csr_s2, xl2, xr2, g2_att, g2_b, p2_w, h2, xls2, K1N);

  // ---- Pool 2 ----
  pool_score<<<cdiv(K1N, 256), b256, 0, stream>>>(rowptr2, csr_s2, xls2,
                                                  p2_asrc, p2_adst, p2_b, p2_sel, scr2, K1N);
  tk_topk<<<1, 1024, 0, stream>>>(scr2, K1N, K2N, newid2, perm2, nullptr, 0);
  col_pool<<<128, b256, 0, stream>>>(h2, perm2, scr2, K2N, HIDD, g2max, g2sum);

  // ---- MLP head ----
  mlp_l1<<<32, b256, 0, stream>>>(pools, l1_w, l1_b, z1);
  mlp_layer<512><<<16, b256, 0, stream>>>(z1, l2_w, l2_b, z2, 256);
  mlp_layer<256><<<8, b256, 0, stream>>>(z2, l3_w, l3_b, z3, 128);
  mlp_final<<<1, 128, 0, stream>>>(z3, l4_w, l4_b, (float*)d_out);
}

// Round 12
// 478.127 us; speedup vs baseline: 1.1668x; 1.0017x over previous
//
#include <hip/hip_runtime.h>
#include <math.h>

#define N_NODES 20000
#define E_EDGES 320000
#define DIN     256
#define HHD     512
#define HIDD    64
#define NHEADS  8
#define K1N     15000
#define K2N     11250

typedef unsigned short u16;
typedef __attribute__((ext_vector_type(8))) short bf16x8;
typedef __attribute__((ext_vector_type(4))) float f32x4;

static inline int cdiv(long long a, long long b) { return (int)((a + b - 1) / b); }

__device__ __forceinline__ void atomicMaxF(float* addr, float val) {
  int* ai = (int*)addr;
  int old = __float_as_int(*addr);
  while (__int_as_float(old) < val) {
    int assumed = old;
    old = atomicCAS(ai, assumed, __float_as_int(val));
    if (old == assumed) break;
  }
}

__device__ __forceinline__ u16 f2bf(float x) {   // RNE f32 -> bf16 bits
  unsigned u = __float_as_uint(x);
  return (u16)((u + 0x7FFFu + ((u >> 16) & 1u)) >> 16);
}
__device__ __forceinline__ float bfval(u16 b) { return __uint_as_float(((unsigned)b) << 16); }

__device__ __forceinline__ void unpk8(uint4 u, float* v) {
  v[0] = __uint_as_float(u.x << 16); v[1] = __uint_as_float(u.x & 0xffff0000u);
  v[2] = __uint_as_float(u.y << 16); v[3] = __uint_as_float(u.y & 0xffff0000u);
  v[4] = __uint_as_float(u.z << 16); v[5] = __uint_as_float(u.z & 0xffff0000u);
  v[6] = __uint_as_float(u.w << 16); v[7] = __uint_as_float(u.w & 0xffff0000u);
}

// order-preserving float->uint key (ascending float == ascending key)
__device__ __forceinline__ unsigned fkey(float s) {
  unsigned b = __float_as_uint(s);
  return (b & 0x80000000u) ? ~b : (b | 0x80000000u);
}

// deg1=0, pools[1152]: [-inf x512, 0 x512, -inf x64, 0 x64]
__global__ void init_all(int* deg1, float* pools) {
  int i = blockIdx.x * blockDim.x + threadIdx.x;
  if (i < N_NODES) deg1[i] = 0;
  else {
    int idx = i - N_NODES;
    if (idx < 1152)
      pools[idx] = (idx < 512 || (idx >= 1024 && idx < 1088)) ? -INFINITY : 0.f;
  }
}

// ---------------- fused bf16 hi/lo split conversion (A-part + W-part in one launch) ----------------
__global__ void conv_fused(const float* __restrict__ A, const int* __restrict__ perm,
                           const float* __restrict__ scalev,
                           u16* __restrict__ ah, u16* __restrict__ al, int M, int K,
                           const float* __restrict__ w1, const float* __restrict__ w2,
                           u16* __restrict__ wh, u16* __restrict__ wl, int ncHalf,
                           int aBlocks) {
  if ((int)blockIdx.x < aBlocks) {
    long long i = (long long)blockIdx.x * blockDim.x + threadIdx.x;
    long long e0 = i * 4;
    if (e0 >= (long long)M * K) return;
    int row = (int)(e0 / K), col = (int)(e0 % K);
    int ar = perm ? perm[row] : row;
    float4 v = *(const float4*)(A + (size_t)ar * K + col);
    if (scalev) { float s = scalev[ar]; v.x *= s; v.y *= s; v.z *= s; v.w *= s; }
    u16 h0 = f2bf(v.x), h1 = f2bf(v.y), h2 = f2bf(v.z), h3 = f2bf(v.w);
    u16 l0 = f2bf(v.x - bfval(h0)), l1 = f2bf(v.y - bfval(h1));
    u16 l2 = f2bf(v.z - bfval(h2)), l3 = f2bf(v.w - bfval(h3));
    uint2 hp, lp;
    hp.x = (unsigned)h0 | ((unsigned)h1 << 16); hp.y = (unsigned)h2 | ((unsigned)h3 << 16);
    lp.x = (unsigned)l0 | ((unsigned)l1 << 16); lp.y = (unsigned)l2 | ((unsigned)l3 << 16);
    *(uint2*)(ah + e0) = hp;
    *(uint2*)(al + e0) = lp;
  } else {
    int i = (blockIdx.x - aBlocks) * blockDim.x + threadIdx.x;
    int NT = 2 * ncHalf;
    if (i >= NT * K) return;
    int n = i % NT, k = i / NT;
    float v = (n < ncHalf) ? w1[(size_t)k * ncHalf + n] : w2[(size_t)k * ncHalf + (n - ncHalf)];
    u16 h = f2bf(v);
    u16 l = f2bf(v - bfval(h));
    wh[(size_t)n * K + k] = h;
    wl[(size_t)n * K + k] = l;
  }
}

// ---------------- split-bf16 MFMA GEMM: C = A @ [W1|W2] ----------------
// NPROD=3: ah*bh + ah*bl + al*bh (full Markidis). NPROD=2: (ah+al)*bh — B-side
// error ~2^-9 rel, acceptable when C is rounded to bf16 anyway (OUTBF).
// LDS rows padded to 42 u16 (84B = 21 dwords, odd) -> even bank tiling on b128 ops.
template<int BT, bool OUTBF, int NPROD>
__global__ __launch_bounds__(256) void gemm_bf16x3(const u16* __restrict__ ah,
                                                   const u16* __restrict__ al,
                                                   const u16* __restrict__ wh,
                                                   const u16* __restrict__ wl,
                                                   void* __restrict__ c1v,
                                                   void* __restrict__ c2v,
                                                   int M, int K, int ncHalf) {
  constexpr int F = BT / 32;
  __shared__ u16 Ah[BT][42], Al[BT][42], Bh[BT][42];
  __shared__ u16 Bl[NPROD == 3 ? BT : 1][NPROD == 3 ? 42 : 1];
  int tid = threadIdx.x;
  int lane = tid & 63, wid = tid >> 6;
  int wr = (wid >> 1) * (BT / 2), wc = (wid & 1) * (BT / 2);
  int brow = blockIdx.y * BT, bcol = blockIdx.x * BT;
  int fr = lane & 15, kg = lane >> 4;
  f32x4 acc[F][F];
#pragma unroll
  for (int i = 0; i < F; i++)
#pragma unroll
    for (int j = 0; j < F; j++) acc[i][j] = (f32x4){0.f, 0.f, 0.f, 0.f};

  for (int k0 = 0; k0 < K; k0 += 32) {
    constexpr int ITER = (BT * 32) / (256 * 8);
#pragma unroll
    for (int i = 0; i < ITER; i++) {
      int pos = tid + i * 256;
      int row = pos >> 2;
      int kc = (pos & 3) * 8;
      int gr = brow + row;
      float4 z = make_float4(0.f, 0.f, 0.f, 0.f);
      float4 vah = (gr < M) ? *(const float4*)(ah + (size_t)gr * K + k0 + kc) : z;
      float4 val = (gr < M) ? *(const float4*)(al + (size_t)gr * K + k0 + kc) : z;
      *(float4*)(&Ah[row][kc]) = vah;
      *(float4*)(&Al[row][kc]) = val;
      int gn = bcol + row;
      *(float4*)(&Bh[row][kc]) = *(const float4*)(wh + (size_t)gn * K + k0 + kc);
      if (NPROD == 3)
        *(float4*)(&Bl[row][kc]) = *(const float4*)(wl + (size_t)gn * K + k0 + kc);
    }
    __syncthreads();
    bf16x8 fa_h[F], fa_l[F], fb_h[F], fb_l[F];
#pragma unroll
    for (int t = 0; t < F; t++) {
      fa_h[t] = *(const bf16x8*)(&Ah[wr + t * 16 + fr][kg * 8]);
      fa_l[t] = *(const bf16x8*)(&Al[wr + t * 16 + fr][kg * 8]);
      fb_h[t] = *(const bf16x8*)(&Bh[wc + t * 16 + fr][kg * 8]);
      if (NPROD == 3)
        fb_l[t] = *(const bf16x8*)(&Bl[wc + t * 16 + fr][kg * 8]);
    }
#pragma unroll
    for (int i = 0; i < F; i++)
#pragma unroll
      for (int j = 0; j < F; j++) {
        acc[i][j] = __builtin_amdgcn_mfma_f32_16x16x32_bf16(fa_h[i], fb_h[j], acc[i][j], 0, 0, 0);
        acc[i][j] = __builtin_amdgcn_mfma_f32_16x16x32_bf16(fa_l[i], fb_h[j], acc[i][j], 0, 0, 0);
        if (NPROD == 3)
          acc[i][j] = __builtin_amdgcn_mfma_f32_16x16x32_bf16(fa_h[i], fb_l[j], acc[i][j], 0, 0, 0);
      }
    __syncthreads();
  }
#pragma unroll
  for (int i = 0; i < F; i++) {
    int r0 = brow + wr + i * 16 + kg * 4;
#pragma unroll
    for (int j = 0; j < F; j++) {
      int cg = bcol + wc + j * 16 + fr;
      bool first = (cg < ncHalf);
      int cc = first ? cg : cg - ncHalf;
#pragma unroll
      for (int r = 0; r < 4; r++) {
        int gr = r0 + r;
        if (gr < M) {
          if (OUTBF) {
            u16* cp = first ? (u16*)c1v : (u16*)c2v;
            cp[(size_t)gr * ncHalf + cc] = f2bf(acc[i][j][r]);
          } else {
            float* cp = first ? (float*)c1v : (float*)c2v;
            cp[(size_t)gr * ncHalf + cc] = acc[i][j][r];
          }
        }
      }
    }
  }
}

// ---------------- CSR construction (stores mapped source id directly) ----------------
__global__ void deg_count(const int* __restrict__ src, const int* __restrict__ dst,
                          const int* __restrict__ newid, int* __restrict__ deg,
                          int nloops) {
  int i = blockIdx.x * blockDim.x + threadIdx.x;
  if (i >= E_EDGES + nloops) return;
  int d;
  if (i < E_EDGES) {
    if (newid) {
      int s = newid[src[i]]; d = newid[dst[i]];
      if (s < 0 || d < 0) return;
    } else d = dst[i];
  } else d = i - E_EDGES;
  atomicAdd(&deg[d], 1);
}

// shuffle-based single-block exclusive scan; cursor may alias deg.
__global__ __launch_bounds__(1024) void scan_excl(const int* deg, int* rowptr,
                                                  int* cursor, int n) {
  __shared__ int wsum[16];
  __shared__ int carry;
  int tid = threadIdx.x, lane = tid & 63, wid = tid >> 6;
  if (tid == 0) { carry = 0; rowptr[0] = 0; }
  __syncthreads();
  for (int base = 0; base < n; base += 1024) {
    int v = (base + tid < n) ? deg[base + tid] : 0;
    int s = v;
#pragma unroll
    for (int off = 1; off < 64; off <<= 1) {
      int t = __shfl_up(s, off);
      if (lane >= off) s += t;
    }
    if (lane == 63) wsum[wid] = s;
    __syncthreads();
    if (wid == 0) {
      int w = (lane < 16) ? wsum[lane] : 0;
#pragma unroll
      for (int off = 1; off < 16; off <<= 1) {
        int t = __shfl_up(w, off);
        if (lane >= off) w += t;
      }
      if (lane < 16) wsum[lane] = w;
    }
    __syncthreads();
    int incl = s + (wid > 0 ? wsum[wid - 1] : 0) + carry;
    if (base + tid < n) { rowptr[base + tid + 1] = incl; cursor[base + tid] = incl - v; }
    __syncthreads();
    if (tid == 1023) carry = incl;
    __syncthreads();
  }
}

__global__ void csr_scatter(const int* __restrict__ src, const int* __restrict__ dst,
                            const int* __restrict__ newid, int* __restrict__ cursor,
                            int* __restrict__ csr_s, int nloops) {
  int i = blockIdx.x * blockDim.x + threadIdx.x;
  if (i >= E_EDGES + nloops) return;
  int s, d;
  if (i < E_EDGES) {
    s = src[i]; d = dst[i];
    if (newid) {
      s = newid[s]; d = newid[d];
      if (s < 0 || d < 0) return;
    }
  } else s = d = i - E_EDGES;
  int pos = atomicAdd(&cursor[d], 1);
  csr_s[pos] = s;
}

// ---------------- Stage 1 fused GAT: 1 wave/node, bf16 gather, 4-deep prefetch ----------------
__global__ __launch_bounds__(256) void gat1_fused(const int* __restrict__ rowptr,
                                                  const int* __restrict__ csr_s,
                                                  const u16* __restrict__ xlb,
                                                  const u16* __restrict__ xrb,
                                                  const float* __restrict__ att,
                                                  const float* __restrict__ bias,
                                                  const float* __restrict__ pw,
                                                  float* __restrict__ out,
                                                  float* __restrict__ xls) {
  int lane = threadIdx.x & 63;
  long long t = (long long)blockIdx.x * blockDim.x + threadIdx.x;
  int d = (int)(t >> 6);
  if (d >= N_NODES) return;
  int base = lane * 8;                       // 8 cols/lane, head = lane>>3
  float4 a0 = *(const float4*)(att + base);
  float4 a1 = *(const float4*)(att + base + 4);
  float r[8];
  unpk8(*(const uint4*)(xrb + (size_t)d * HHD + base), r);
  float m = -INFINITY, den = 0.f;
  float acc[8] = {0.f, 0.f, 0.f, 0.f, 0.f, 0.f, 0.f, 0.f};
  int b0 = rowptr[d];
  int cnt = rowptr[d + 1] - b0;
  const int* sp = csr_s + b0;

  auto online = [&](uint4 u) {
    float v[8];
    unpk8(u, v);
    float p, tv;
    tv = v[0] + r[0]; tv = tv > 0.f ? tv : 0.2f * tv; p  = tv * a0.x;
    tv = v[1] + r[1]; tv = tv > 0.f ? tv : 0.2f * tv; p += tv * a0.y;
    tv = v[2] + r[2]; tv = tv > 0.f ? tv : 0.2f * tv; p += tv * a0.z;
    tv = v[3] + r[3]; tv = tv > 0.f ? tv : 0.2f * tv; p += tv * a0.w;
    tv = v[4] + r[4]; tv = tv > 0.f ? tv : 0.2f * tv; p += tv * a1.x;
    tv = v[5] + r[5]; tv = tv > 0.f ? tv : 0.2f * tv; p += tv * a1.y;
    tv = v[6] + r[6]; tv = tv > 0.f ? tv : 0.2f * tv; p += tv * a1.z;
    tv = v[7] + r[7]; tv = tv > 0.f ? tv : 0.2f * tv; p += tv * a1.w;
    p += __shfl_xor(p, 1); p += __shfl_xor(p, 2); p += __shfl_xor(p, 4);
    float nm = fmaxf(m, p);
    float w  = __expf(p - nm);
    float sc = __expf(m - nm);
    den = den * sc + w;
#pragma unroll
    for (int k = 0; k < 8; k++) acc[k] = acc[k] * sc + w * v[k];
    m = nm;
  };

  uint4 zz = make_uint4(0u, 0u, 0u, 0u);
  uint4 A = *(const uint4*)(xlb + (size_t)sp[0] * HHD + base);
  uint4 B = (cnt > 1) ? *(const uint4*)(xlb + (size_t)sp[1] * HHD + base) : zz;
  uint4 C = (cnt > 2) ? *(const uint4*)(xlb + (size_t)sp[2] * HHD + base) : zz;
  uint4 D = (cnt > 3) ? *(const uint4*)(xlb + (size_t)sp[3] * HHD + base) : zz;
  int j = 0;
  for (; j + 4 <= cnt; j += 4) {
    uint4 u = A;
    if (j + 4 < cnt) A = *(const uint4*)(xlb + (size_t)sp[j + 4] * HHD + base);
    online(u);
    u = B;
    if (j + 5 < cnt) B = *(const uint4*)(xlb + (size_t)sp[j + 5] * HHD + base);
    online(u);
    u = C;
    if (j + 6 < cnt) C = *(const uint4*)(xlb + (size_t)sp[j + 6] * HHD + base);
    online(u);
    u = D;
    if (j + 7 < cnt) D = *(const uint4*)(xlb + (size_t)sp[j + 7] * HHD + base);
    online(u);
  }
  if (j < cnt) {
    online(A);
    if (j + 1 < cnt) {
      online(B);
      if (j + 2 < cnt) online(C);
    }
  }

  float inv = 1.f / den;
  float4 b0v = *(const float4*)(bias + base);
  float4 b1v = *(const float4*)(bias + base + 4);
  float o[8];
  o[0] = acc[0] * inv + b0v.x; o[1] = acc[1] * inv + b0v.y;
  o[2] = acc[2] * inv + b0v.z; o[3] = acc[3] * inv + b0v.w;
  o[4] = acc[4] * inv + b1v.x; o[5] = acc[5] * inv + b1v.y;
  o[6] = acc[6] * inv + b1v.z; o[7] = acc[7] * inv + b1v.w;
#pragma unroll
  for (int k = 0; k < 8; k++) o[k] = o[k] > 0.f ? o[k] : 0.f;
  float* op = out + (size_t)d * HHD + base;
  *(float4*)(op)     = make_float4(o[0], o[1], o[2], o[3]);
  *(float4*)(op + 4) = make_float4(o[4], o[5], o[6], o[7]);
  float4 w0 = *(const float4*)(pw + base);
  float4 w1 = *(const float4*)(pw + base + 4);
  float sdot = o[0]*w0.x + o[1]*w0.y + o[2]*w0.z + o[3]*w0.w
             + o[4]*w1.x + o[5]*w1.y + o[6]*w1.z + o[7]*w1.w;
#pragma unroll
  for (int off = 32; off > 0; off >>= 1) sdot += __shfl_xor(sdot, off);
  if (lane == 0) xls[d] = sdot;
}

// ---------------- Stage 2 fused GAT: 4 nodes per wave (one per 16-lane group) ----------------
__global__ __launch_bounds__(256) void gat2_fused(const int* __restrict__ rowptr,
                                                  const int* __restrict__ csr_s,
                                                  const float* __restrict__ xl,
                                                  const float* __restrict__ xr,
                                                  const float* __restrict__ att,
                                                  const float* __restrict__ bias,
                                                  const float* __restrict__ pw,
                                                  float* __restrict__ out,
                                                  float* __restrict__ xls, int n) {
  int lane = threadIdx.x & 63;
  int grp = lane >> 4, li = lane & 15;
  long long t = (long long)blockIdx.x * blockDim.x + threadIdx.x;
  int wv = (int)(t >> 6);
  int d = wv * 4 + grp;
  if (d >= n) return;
  int c0 = li * 4;
  float4 av = *(const float4*)(att + c0);
  float4 rv = *(const float4*)(xr + (size_t)d * HIDD + c0);
  float m = -INFINITY, den = 0.f;
  float4 acc = make_float4(0.f, 0.f, 0.f, 0.f);
  int b0 = rowptr[d];
  int cnt = rowptr[d + 1] - b0;
  const int* sp = csr_s + b0;

  auto online = [&](float4 v) {
    float p, tv;
    tv = v.x + rv.x; tv = tv > 0.f ? tv : 0.2f * tv; p  = tv * av.x;
    tv = v.y + rv.y; tv = tv > 0.f ? tv : 0.2f * tv; p += tv * av.y;
    tv = v.z + rv.z; tv = tv > 0.f ? tv : 0.2f * tv; p += tv * av.z;
    tv = v.w + rv.w; tv = tv > 0.f ? tv : 0.2f * tv; p += tv * av.w;
    p += __shfl_xor(p, 1); p += __shfl_xor(p, 2); p += __shfl_xor(p, 4); p += __shfl_xor(p, 8);
    float nm = fmaxf(m, p);
    float w  = __expf(p - nm);
    float sc = __expf(m - nm);
    den = den * sc + w;
    acc.x = acc.x * sc + w * v.x;
    acc.y = acc.y * sc + w * v.y;
    acc.z = acc.z * sc + w * v.z;
    acc.w = acc.w * sc + w * v.w;
    m = nm;
  };

  float4 zz = make_float4(0.f, 0.f, 0.f, 0.f);
  float4 A = *(const float4*)(xl + (size_t)sp[0] * HIDD + c0);
  float4 B = (cnt > 1) ? *(const float4*)(xl + (size_t)sp[1] * HIDD + c0) : zz;
  int j = 0;
  for (; j + 2 <= cnt; j += 2) {
    float4 v = A;
    if (j + 2 < cnt) A = *(const float4*)(xl + (size_t)sp[j + 2] * HIDD + c0);
    online(v);
    v = B;
    if (j + 3 < cnt) B = *(const float4*)(xl + (size_t)sp[j + 3] * HIDD + c0);
    online(v);
  }
  if (j < cnt) online(A);

  float inv = 1.f / den;
  float4 bv = *(const float4*)(bias + c0);
  float4 o;
  o.x = acc.x * inv + bv.x; o.y = acc.y * inv + bv.y;
  o.z = acc.z * inv + bv.z; o.w = acc.w * inv + bv.w;
  o.x = o.x > 0.f ? o.x : 0.f; o.y = o.y > 0.f ? o.y : 0.f;
  o.z = o.z > 0.f ? o.z : 0.f; o.w = o.w > 0.f ? o.w : 0.f;
  *(float4*)(out + (size_t)d * HIDD + c0) = o;
  float4 wv4 = *(const float4*)(pw + c0);
  float sdot = o.x * wv4.x + o.y * wv4.y + o.z * wv4.z + o.w * wv4.w;
  sdot += __shfl_xor(sdot, 1); sdot += __shfl_xor(sdot, 2);
  sdot += __shfl_xor(sdot, 4); sdot += __shfl_xor(sdot, 8);
  if (li == 0) xls[d] = sdot;
}

// ---------------- pool scoring: online softmax + tanh, 4-deep prefetch ----------------
__global__ __launch_bounds__(256) void pool_score(const int* __restrict__ rowptr,
                                                  const int* __restrict__ csr_s,
                                                  const float* __restrict__ xls,
                                                  const float* __restrict__ asrc,
                                                  const float* __restrict__ adst,
                                                  const float* __restrict__ bias,
                                                  const float* __restrict__ sel,
                                                  float* __restrict__ score, int n) {
  int d = blockIdx.x * blockDim.x + threadIdx.x;
  if (d >= n) return;
  float as = asrc[0], ad = adst[0];
  float ar = xls[d] * ad;
  int b0 = rowptr[d];
  int cnt = rowptr[d + 1] - b0;
  const int* sp = csr_s + b0;
  float m = -INFINITY, den = 0.f, num = 0.f;
  auto upd = [&](float xs) {
    float e = xs * as + ar;
    e = e > 0.f ? e : 0.2f * e;
    float nm = fmaxf(m, e);
    float scv = __expf(m - nm);
    float ex = __expf(e - nm);
    den = den * scv + ex;
    num = num * scv + ex * xs;
    m = nm;
  };
  float xA = xls[sp[0]];
  float xB = (cnt > 1) ? xls[sp[1]] : 0.f;
  float xC = (cnt > 2) ? xls[sp[2]] : 0.f;
  float xD = (cnt > 3) ? xls[sp[3]] : 0.f;
  int j = 0;
  for (; j + 4 <= cnt; j += 4) {
    float x1 = xA;
    if (j + 4 < cnt) xA = xls[sp[j + 4]];
    upd(x1);
    float x2 = xB;
    if (j + 5 < cnt) xB = xls[sp[j + 5]];
    upd(x2);
    float x3 = xC;
    if (j + 6 < cnt) xC = xls[sp[j + 6]];
    upd(x3);
    float x4 = xD;
    if (j + 7 < cnt) xD = xls[sp[j + 7]];
    upd(x4);
  }
  if (j < cnt) {
    upd(xA);
    if (j + 1 < cnt) {
      upd(xB);
      if (j + 2 < cnt) upd(xC);
    }
  }
  float attn = num / den + bias[0];
  float sv = sel[0];
  score[d] = tanhf(attn * sv / fabsf(sv));
}

// ---------------- exact top-k via single-block radix select (O(N)) ----------------
__global__ __launch_bounds__(1024) void tk_topk(const float* __restrict__ score, int n, int k,
                                                int* __restrict__ newid, int* __restrict__ perm,
                                                int* __restrict__ zbuf, int zn) {
  __shared__ unsigned bins[2048];
  __shared__ unsigned wsum[16];
  __shared__ unsigned sb[4];
  int tid = threadIdx.x, lane = tid & 63, wid = tid >> 6;

  for (int i = tid; i < zn; i += 1024) zbuf[i] = 0;

  unsigned pref = 0;
  unsigned kneed = (unsigned)k;

  for (int level = 0; level < 3; level++) {
    const int shift = (level == 0) ? 21 : (level == 1) ? 10 : 0;
    const unsigned mask = (level == 2) ? 1023u : 2047u;
    for (int b = tid; b < 2048; b += 1024) bins[b] = 0;
    __syncthreads();
    for (int i = tid; i < n; i += 1024) {
      unsigned key = fkey(score[i]);
      bool match = (level == 0) ? true
                 : (level == 1) ? ((key >> 21) == pref)
                                : ((key >> 10) == pref);
      if (match) atomicAdd(&bins[(key >> shift) & mask], 1u);
    }
    __syncthreads();
    unsigned c0 = bins[2 * tid], c1 = bins[2 * tid + 1];
    unsigned v = c0 + c1;
    unsigned s = v;
#pragma unroll
    for (int off = 1; off < 64; off <<= 1) {
      unsigned t2 = __shfl_up(s, off);
      if (lane >= off) s += t2;
    }
    if (lane == 63) wsum[wid] = s;
    __syncthreads();
    if (wid == 0) {
      unsigned w = (lane < 16) ? wsum[lane] : 0;
#pragma unroll
      for (int off = 1; off < 16; off <<= 1) {
        unsigned t2 = __shfl_up(w, off);
        if (lane >= off) w += t2;
      }
      if (lane < 16) wsum[lane] = w;
    }
    __syncthreads();
    unsigned incl = s + (wid > 0 ? wsum[wid - 1] : 0);
    unsigned excl = incl - v;
    if (tid == 1023) sb[0] = incl;           // TOT (matched count)
    __syncthreads();
    unsigned TOT = sb[0];
    unsigned target = TOT - kneed;
    unsigned ip0 = excl + c0;
    unsigned ip1 = ip0 + c1;
    if (excl <= target && target < ip0) { sb[1] = 2u * tid;     sb[2] = TOT - ip0; }
    if (ip0  <= target && target < ip1) { sb[1] = 2u * tid + 1; sb[2] = TOT - ip1; }
    __syncthreads();
    pref = (pref << ((level == 2) ? 10 : 11)) | sb[1];
    kneed -= sb[2];
    __syncthreads();
  }
  const unsigned U = pref, rem = kneed;

  unsigned carry = 0;
  for (int base = 0; base < n; base += 1024) {
    int i = base + tid;
    bool valid = i < n;
    unsigned key = valid ? fkey(score[i]) : 0u;
    unsigned gt  = (valid && key >  U) ? 1u : 0u;
    unsigned tie = (valid && key == U) ? 1u : 0u;
    unsigned v = gt | (tie << 16);
    unsigned s = v;
#pragma unroll
    for (int off = 1; off < 64; off <<= 1) {
      unsigned t2 = __shfl_up(s, off);
      if (lane >= off) s += t2;
    }
    if (lane == 63) wsum[wid] = s;
    __syncthreads();
    if (wid == 0) {
      unsigned w = (lane < 16) ? wsum[lane] : 0;
#pragma unroll
      for (int off = 1; off < 16; off <<= 1) {
        unsigned t2 = __shfl_up(w, off);
        if (lane >= off) w += t2;
      }
      if (lane < 16) wsum[lane] = w;
    }
    __syncthreads();
    unsigned incl = s + (wid > 0 ? wsum[wid - 1] : 0);
    unsigned pfx = (incl - v) + carry;
    unsigned gtpfx = pfx & 0xFFFFu, tiepfx = pfx >> 16;
    unsigned tsel = (tiepfx < rem) ? tiepfx : rem;
    bool selq = gt || (tie && tiepfx < rem);
    unsigned id = gtpfx + tsel;
    if (valid) {
      newid[i] = selq ? (int)id : -1;
      if (selq) perm[id] = i;
    }
    if (tid == 1023) sb[0] = incl + carry;
    __syncthreads();
    carry = sb[0];
    __syncthreads();
  }
}

// stage-1 column pool fused with stage-2 A-conversion (+W2 conversion in extra blocks)
__global__ __launch_bounds__(256) void col_pool_conv(const float* __restrict__ X,
                                                     const int* __restrict__ perm,
                                                     const float* __restrict__ scalev,
                                                     float* __restrict__ omax,
                                                     float* __restrict__ osum,
                                                     u16* __restrict__ ah, u16* __restrict__ al,
                                                     const float* __restrict__ w1,
                                                     const float* __restrict__ w2,
                                                     u16* __restrict__ wh, u16* __restrict__ wl,
                                                     int cpBlocks) {
  int tid = threadIdx.x;
  if ((int)blockIdx.x < cpBlocks) {
    float mx[2] = {-INFINITY, -INFINITY};
    float sm[2] = {0.f, 0.f};
    int rpb = (K1N + cpBlocks - 1) / cpBlocks;
    int rbeg = blockIdx.x * rpb;
    int rend = min(K1N, rbeg + rpb);
    for (int r = rbeg; r < rend; r++) {
      int orow = perm[r];
      float sc = scalev[orow];
      const float* row = X + (size_t)orow * HHD;
#pragma unroll
      for (int sg = 0; sg < 2; sg++) {
        int c = sg * 256 + tid;
        float v = row[c] * sc;
        mx[sg] = fmaxf(mx[sg], v);
        sm[sg] += v;
        u16 h = f2bf(v);
        u16 l = f2bf(v - bfval(h));
        ah[(size_t)r * HHD + c] = h;
        al[(size_t)r * HHD + c] = l;
      }
    }
    if (rbeg < rend) {
#pragma unroll
      for (int sg = 0; sg < 2; sg++) {
        int c = sg * 256 + tid;
        atomicMaxF(&omax[c], mx[sg]);
        atomicAdd(&osum[c], sm[sg]);
      }
    }
  } else {
    int i = (blockIdx.x - cpBlocks) * 256 + tid;
    const int NT = 2 * HIDD;
    if (i >= NT * HHD) return;
    int n = i % NT, k = i / NT;
    float v = (n < HIDD) ? w1[(size_t)k * HIDD + n] : w2[(size_t)k * HIDD + (n - HIDD)];
    u16 h = f2bf(v);
    u16 l = f2bf(v - bfval(h));
    wh[(size_t)n * HHD + k] = h;
    wl[(size_t)n * HHD + k] = l;
  }
}

// plain column pool (stage 2)
__global__ __launch_bounds__(256) void col_pool(const float* __restrict__ X,
                                                const int* __restrict__ perm,
                                                const float* __restrict__ scalev,
                                                int rows, int C,
                                                float* __restrict__ omax, float* __restrict__ osum) {
  int tid = threadIdx.x;
  float mx = -INFINITY, sm = 0.f;
  int rpb = (rows + gridDim.x - 1) / gridDim.x;
  int rbeg = blockIdx.x * rpb;
  int rend = min(rows, rbeg + rpb);
  for (int r = rbeg; r < rend; r++) {
    int orow = perm[r];
    float sc = scalev[orow];
    int c = tid;
    if (c < C) {
      float v = X[(size_t)orow * C + c] * sc;
      mx = fmaxf(mx, v);
      sm += v;
    }
  }
  if (rbeg < rend && tid < C) {
    atomicMaxF(&omax[tid], mx);
    atomicAdd(&osum[tid], sm);
  }
}

// ---------------- MLP head ----------------
__global__ __launch_bounds__(256) void mlp_l1(const float* __restrict__ pools,
                                              const float* __restrict__ w1,
                                              const float* __restrict__ b1,
                                              float* __restrict__ z1out) {
  __shared__ float z[1024];
  __shared__ float red[16][17];
  int t = threadIdx.x;
  for (int i = t; i < 1024; i += 256) {
    float xv = (i < 512) ? pools[i] : pools[i] * (1.f / K1N);
    float gv = (i < 512) ? pools[1024 + (i & 63)] : pools[1088 + (i & 63)] * (1.f / K2N);
    z[i] = xv + gv;
  }
  __syncthreads();
  int jl = t & 15, ch = t >> 4;
  int j = blockIdx.x * 16 + jl;
  float p = 0.f;
  for (int k = ch * 64; k < ch * 64 + 64; k++) p += z[k] * w1[(size_t)k * 512 + j];
  red[ch][jl] = p;
  __syncthreads();
  if (t < 16) {
    float s = b1[blockIdx.x * 16 + t];
    for (int c = 0; c < 16; c++) s += red[c][t];
    z1out[blockIdx.x * 16 + t] = s > 0.f ? s : 0.f;
  }
}

template<int NIN>
__global__ __launch_bounds__(256) void mlp_layer(const float* __restrict__ in,
                                                 const float* __restrict__ w,
                                                 const float* __restrict__ b,
                                                 float* __restrict__ out, int nout) {
  __shared__ float red[16][17];
  int t = threadIdx.x;
  int jl = t & 15, ch = t >> 4;
  int j = blockIdx.x * 16 + jl;
  constexpr int CH = NIN / 16;
  float p = 0.f;
  for (int k = ch * CH; k < (ch + 1) * CH; k++) p += in[k] * w[(size_t)k * nout + j];
  red[ch][jl] = p;
  __syncthreads();
  if (t < 16) {
    float s = b[blockIdx.x * 16 + t];
    for (int c = 0; c < 16; c++) s += red[c][t];
    out[blockIdx.x * 16 + t] = s > 0.f ? s : 0.f;
  }
}

__global__ __launch_bounds__(128) void mlp_final(const float* __restrict__ z3,
                                                 const float* __restrict__ w4,
                                                 const float* __restrict__ b4,
                                                 float* __restrict__ out) {
  int t = threadIdx.x;
  float v = z3[t];
  float p0 = v * w4[2 * t], p1 = v * w4[2 * t + 1];
#pragma unroll
  for (int off = 32; off > 0; off >>= 1) {
    p0 += __shfl_xor(p0, off);
    p1 += __shfl_xor(p1, off);
  }
  __shared__ float s0[2], s1[2];
  if ((t & 63) == 0) { s0[t >> 6] = p0; s1[t >> 6] = p1; }
  __syncthreads();
  if (t == 0) {
    float l0 = s0[0] + s0[1] + b4[0], l1 = s1[0] + s1[1] + b4[1];
    float m = fmaxf(l0, l1);
    float e0 = __expf(l0 - m), e1 = __expf(l1 - m);
    float s = e0 + e1;
    out[0] = l0; out[1] = l1;
    out[2] = e0 / s; out[3] = e1 / s;
  }
}

extern "C" void kernel_launch(void* const* d_in, const int* in_sizes, int n_in,
                              void* d_out, int out_size, void* d_ws, size_t ws_size,
                              hipStream_t stream) {
  const float* x       = (const float*)d_in[0];
  const int*   ei      = (const int*)d_in[1];
  const float* g1_wl   = (const float*)d_in[2];
  const float* g1_wr   = (const float*)d_in[3];
  const float* g1_att  = (const float*)d_in[4];
  const float* g1_b    = (const float*)d_in[5];
  const float* p1_w    = (const float*)d_in[6];
  const float* p1_asrc = (const float*)d_in[7];
  const float* p1_adst = (const float*)d_in[8];
  const float* p1_b    = (const float*)d_in[9];
  const float* p1_sel  = (const float*)d_in[10];
  const float* g2_wl   = (const float*)d_in[11];
  const float* g2_wr   = (const float*)d_in[12];
  const float* g2_att  = (const float*)d_in[13];
  const float* g2_b    = (const float*)d_in[14];
  const float* p2_w    = (const float*)d_in[15];
  const float* p2_asrc = (const float*)d_in[16];
  const float* p2_adst = (const float*)d_in[17];
  const float* p2_b    = (const float*)d_in[18];
  const float* p2_sel  = (const float*)d_in[19];
  const float* l1_w    = (const float*)d_in[20];
  const float* l1_b    = (const float*)d_in[21];
  const float* l2_w    = (const float*)d_in[22];
  const float* l2_b    = (const float*)d_in[23];
  const float* l3_w    = (const float*)d_in[24];
  const float* l3_b    = (const float*)d_in[25];
  const float* l4_w    = (const float*)d_in[26];
  const float* l4_b    = (const float*)d_in[27];

  const int* src = ei;
  const int* dst = ei + E_EDGES;

  if (ws_size < (size_t)33440000 * 4) return;
  float* ws  = (float*)d_ws;
  float* xl1 = ws;                 // region A: xl1b bf16; later stage-2 bf16 arena
  float* xr1 = ws + 10240000;      // region B: xr1b bf16; later stage-2 f32 arena
  float* h1  = ws + 20480000;      // region C: stage-1 bf16 input arena, then h1 f32
  float* aux = ws + 30720000;      // persistent small buffers

  int*   csr_s1   = (int*)aux;               // 340000
  int*   rowptr1  = (int*)(aux + 340000);    // 20001
  int*   deg1     = (int*)(aux + 360064);    // 20000 (deg -> cursor)
  int*   newid1   = (int*)(aux + 400064);    // 20000
  float* xls1     = aux + 420064;            // 20000
  float* scr1     = aux + 440064;            // 20000
  float* pools    = aux + 460064;            // 1152: x1max|x1sum|g2max|g2sum
  float* x1max    = pools;
  float* x1sum    = pools + 512;
  float* g2max    = pools + 1024;
  float* g2sum    = pools + 1088;
  int*   perm1    = (int*)(aux + 461248);    // 20000
  float* z1       = aux + 481248;            // 512
  float* z2       = aux + 481760;            // 256
  float* z3       = aux + 482016;            // 128

  // stage-1 GEMM outputs, bf16 (regions A/B)
  u16* xl1b = (u16*)xl1;
  u16* xr1b = (u16*)xr1;

  // stage-1 bf16 input arena (region C; dead once gat1_fused writes h1)
  u16* ah1 = (u16*)h1;
  u16* al1 = ah1 + 5120000;
  u16* wh1 = al1 + 5120000;
  u16* wl1 = wh1 + 262144;

  // stage-2 bf16 input arena (region A; xl1b dead after gat1_fused)
  u16* ah2 = (u16*)xl1;
  u16* al2 = ah2 + 7680000;
  u16* wh2 = al2 + 7680000;
  u16* wl2 = wh2 + 65536;

  float* a2 = xr1;                     // stage-2 f32 arena (region B)
  float* xl2      = a2;                      // 960000
  float* xr2      = a2 + 960000;             // 960000
  float* h2       = a2 + 1920000;            // 960000
  int*   csr_s2   = (int*)(a2 + 2880000);    // 335000
  int*   rowptr2  = (int*)(a2 + 3215000);    // 15001
  int*   deg2     = (int*)(a2 + 3230016);    // 15000
  int*   newid2   = (int*)(a2 + 3260016);    // 15000
  float* xls2     = a2 + 3275016;            // 15000
  float* scr2     = a2 + 3290016;            // 15000
  int*   perm2    = (int*)(a2 + 3305016);    // 15000

  dim3 b256(256);
  const int E1 = E_EDGES + N_NODES;   // 340000
  const int E2 = E_EDGES + K1N;       // 335000

  // ---- init + CSR1 ----
  init_all<<<cdiv(N_NODES + 1152, 256), b256, 0, stream>>>(deg1, pools);
  deg_count<<<cdiv(E1, 256), b256, 0, stream>>>(src, dst, nullptr, deg1, N_NODES);
  scan_excl<<<1, 1024, 0, stream>>>(deg1, rowptr1, deg1, N_NODES);
  csr_scatter<<<cdiv(E1, 256), b256, 0, stream>>>(src, dst, nullptr, deg1, csr_s1, N_NODES);

  // ---- Stage 1: conv + bf16-split MFMA GEMM (2-product, bf16 out) + fused GAT ----
  {
    int aBlocks = cdiv((long long)N_NODES * DIN / 4, 256);
    int wBlocks = cdiv(2 * HHD * DIN, 256);
    conv_fused<<<aBlocks + wBlocks, b256, 0, stream>>>(
        x, nullptr, nullptr, ah1, al1, N_NODES, DIN, g1_wl, g1_wr, wh1, wl1, HHD, aBlocks);
  }
  gemm_bf16x3<128, true, 2><<<dim3(2 * HHD / 128, cdiv(N_NODES, 128)), b256, 0, stream>>>(
      ah1, al1, wh1, wl1, xl1b, xr1b, N_NODES, DIN, HHD);
  gat1_fused<<<cdiv((long long)N_NODES * 64, 256), b256, 0, stream>>>(
      rowptr1, csr_s1, xl1b, xr1b, g1_att, g1_b, p1_w, h1, xls1);

  // ---- Pool 1: score -> radix-select top-k (also zeroes deg2 in dead region B) ----
  pool_score<<<cdiv(N_NODES, 256), b256, 0, stream>>>(rowptr1, csr_s1, xls1,
                                                      p1_asrc, p1_adst, p1_b, p1_sel, scr1, N_NODES);
  tk_topk<<<1, 1024, 0, stream>>>(scr1, N_NODES, K1N, newid1, perm1, deg2, 15000);
  {
    int cpBlocks = 256;
    int wBlocks = cdiv(2 * HIDD * HHD, 256);
    col_pool_conv<<<cpBlocks + wBlocks, b256, 0, stream>>>(
        h1, perm1, scr1, x1max, x1sum, ah2, al2, g2_wl, g2_wr, wh2, wl2, cpBlocks);
  }

  // ---- CSR2 + Stage 2 GEMM (3-product, f32 out) + fused GAT (4 nodes/wave) ----
  deg_count<<<cdiv(E2, 256), b256, 0, stream>>>(src, dst, newid1, deg2, K1N);
  scan_excl<<<1, 1024, 0, stream>>>(deg2, rowptr2, deg2, K1N);
  csr_scatter<<<cdiv(E2, 256), b256, 0, stream>>>(src, dst, newid1, deg2, csr_s2, K1N);

  gemm_bf16x3<64, false, 3><<<dim3(2 * HIDD / 64, cdiv(K1N, 64)), b256, 0, stream>>>(
      ah2, al2, wh2, wl2, xl2, xr2, K1N, HHD, HIDD);
  gat2_fused<<<cdiv((long long)K1N * 16, 256), b256, 0, stream>>>(
      rowptr2, csr_s2, xl2, xr2, g2_att, g2_b, p2_w, h2, xls2, K1N);

  // ---- Pool 2 ----
  pool_score<<<cdiv(K1N, 256), b256, 0, stream>>>(rowptr2, csr_s2, xls2,
                                                  p2_asrc, p2_adst, p2_b, p2_sel, scr2, K1N);
  tk_topk<<<1, 1024, 0, stream>>>(scr2, K1N, K2N, newid2, perm2, nullptr, 0);
  col_pool<<<128, b256, 0, stream>>>(h2, perm2, scr2, K2N, HIDD, g2max, g2sum);

  // ---- MLP head ----
  mlp_l1<<<32, b256, 0, stream>>>(pools, l1_w, l1_b, z1);
  mlp_layer<512><<<16, b256, 0, stream>>>(z1, l2_w, l2_b, z2, 256);
  mlp_layer<256><<<8, b256, 0, stream>>>(z2, l3_w, l3_b, z3, 128);
  mlp_final<<<1, 128, 0, stream>>>(z3, l4_w, l4_b, (float*)d_out);
}